// Round 13
// baseline (836.101 us; speedup 1.0000x reference)
//
#include <hip/hip_runtime.h>
#include <hip/hip_fp16.h>
#include <hip/hip_bf16.h>
#include <hip/hip_cooperative_groups.h>

namespace cg = cooperative_groups;

// SlotAttention restructured:
//  dots = qs . x   with qs = LN(slots) @ (scale * Wq^T Wk)   (K never materialized)
//  updates folded:  gates_ih = (agg*fac) @ (Wih@Wv)^T        (V and upd never materialized)
// x = LN(inputs) fp16. fp32 accumulation. Output fp32.
// R12 (regressed): 128-block chunk machine = 1 wave/SIMD. R13: R11's five tail
// kernels kept VERBATIM as phases of one cooperative kernel per iteration
// (grid.sync between phases; 384-block grid; 52KB LDS union; no min-waves
// launch_bounds -> no R10 VGPR clamp). Dispatches 21 -> 9.

#define BB 64
#define NN 4096
#define DD 256
#define NSL 8
#define NITER 3

__device__ __forceinline__ float wredsum(float v){
#pragma unroll
  for(int m=32;m;m>>=1) v += __shfl_xor(v, m, 64);
  return v;
}
__device__ __forceinline__ float2 u2f2(unsigned u){ __half2 h; __builtin_memcpy(&h,&u,4); return __half22float2(h); }
__device__ __forceinline__ float sigm(float v){ return 1.0f/(1.0f+__expf(-v)); }

union U4 { uint4 u; __half2 h[4]; };

__device__ __forceinline__ void st8(float* dst, uint4 uu){
  U4 v; v.u=uu;
  float2 f0=__half22float2(v.h[0]), f1=__half22float2(v.h[1]),
         f2=__half22float2(v.h[2]), f3=__half22float2(v.h[3]);
  dst[0]=f0.x; dst[1]=f0.y; dst[2]=f1.x; dst[3]=f1.y;
  dst[4]=f2.x; dst[5]=f2.y; dst[6]=f3.x; dst[7]=f3.y;
}

// ---------------- merged prep: weights + slots + WC GEMM + M GEMM + agg zero ----------------
__global__ __launch_bounds__(256) void kp_all(
    const float* __restrict__ Whh, const float* __restrict__ W1,
    const float* __restrict__ W2,  const float* __restrict__ sinit,
    const float* __restrict__ Wih, const float* __restrict__ Wv,
    const float* __restrict__ Wq,  const float* __restrict__ Wk,
    __half* __restrict__ Wg, __half* __restrict__ W1t, __half* __restrict__ W2t,
    float* __restrict__ slots, __half* __restrict__ M2h, float* __restrict__ zbuf){
  int bid=blockIdx.x, t=threadIdx.x;
  if(bid<1664){
    for(int idx=bid*256+t; idx<851968; idx+=1664*256){
      if(idx<196608){ int col=idx>>8, c=idx&255; Wg[(size_t)c*1536+768+col]=__float2half(Whh[idx]); }
      else if(idx<458752){ int k=idx-196608; int col=k>>8, c=k&255; W1t[(size_t)c*1024+col]=__float2half(W1[k]); }
      else if(idx<720896){ int k=idx-458752; int col=k>>10, c=k&1023; W2t[(size_t)c*256+col]=__float2half(W2[k]); }
      else { int k=idx-720896; slots[k]=sinit[k&2047]; }
    }
  } else if(bid<2432){
    int col=bid-1664;            // 0..767
    __shared__ float wr[256];
    wr[t]=Wih[col*256+t];
    __syncthreads();
    float acc=0.f;
#pragma unroll 8
    for(int d=0;d<256;d++) acc += wr[d]*Wv[d*256+t];
    Wg[(size_t)t*1536+col]=__float2half(acc);
  } else if(bid<2688){
    int c=bid-2432;              // 0..255
    float acc=0.f;
#pragma unroll 8
    for(int d=0;d<256;d++) acc += Wq[d*256+t]*Wk[d*256+c];
    M2h[(size_t)c*256+t]=__float2half(acc*0.0625f);
  } else {
    int idx=(bid-2688)*256+t;
    if(idx<394752) zbuf[idx]=0.f;
  }
}

// ---------------- x = LN(inputs) -> fp16 ----------------
__global__ __launch_bounds__(256) void k_ln_x(const float* __restrict__ in, const float* __restrict__ g,
                                              const float* __restrict__ bbv, __half* __restrict__ x){
  int row  = blockIdx.x*4 + (threadIdx.x>>6);
  int lane = threadIdx.x&63;
  const float4 v = ((const float4*)(in + (size_t)row*DD))[lane];
  float s  = v.x+v.y+v.z+v.w;
  float ss = v.x*v.x+v.y*v.y+v.z*v.z+v.w*v.w;
  s = wredsum(s); ss = wredsum(ss);
  float m = s*(1.0f/256.0f);
  float r = rsqrtf(ss*(1.0f/256.0f) - m*m + 1e-5f);
  float4 gv = ((const float4*)g)[lane];
  float4 bv = ((const float4*)bbv)[lane];
  float y0=(v.x-m)*r*gv.x+bv.x, y1=(v.y-m)*r*gv.y+bv.y;
  float y2=(v.z-m)*r*gv.z+bv.z, y3=(v.w-m)*r*gv.w+bv.w;
  __half2 h0=__floats2half2_rn(y0,y1), h1=__floats2half2_rn(y2,y3);
  uint2 u; __builtin_memcpy(&u.x,&h0,4); __builtin_memcpy(&u.y,&h1,4);
  ((uint2*)(x + (size_t)row*DD))[lane] = u;
}

// ---------------- initial qs = LN(slots) @ M (once); also writes slotsh ----------------
__global__ __launch_bounds__(256) void k_pre(const float* __restrict__ slots, const float* __restrict__ g,
                                             const float* __restrict__ bbv, const __half* __restrict__ M2h,
                                             float* __restrict__ qs, __half* __restrict__ slotsh){
  int row = blockIdx.x;      // 0..511
  int t = threadIdx.x;
  __shared__ __align__(16) float sn[256];
  __shared__ float red[8];
  float v = slots[row*256 + t];
  slotsh[(size_t)row*256+t]=__float2half(v);
  float s = wredsum(v), ss = wredsum(v*v);
  int wid=t>>6, lane=t&63;
  if(lane==0){ red[wid]=s; red[4+wid]=ss; }
  __syncthreads();
  float S  = red[0]+red[1]+red[2]+red[3];
  float SS = red[4]+red[5]+red[6]+red[7];
  float m = S*(1.0f/256.0f);
  float r = rsqrtf(SS*(1.0f/256.0f) - m*m + 1e-5f);
  sn[t] = (v-m)*r*g[t]+bbv[t];
  __syncthreads();
  const uint4* w4 = (const uint4*)(M2h + (size_t)t*256);
  float acc=0.f;
#pragma unroll 4
  for(int kk=0;kk<32;kk++){
    U4 w; w.u=w4[kk];
#pragma unroll
    for(int q=0;q<4;q++){
      float2 f=__half22float2(w.h[q]);
      acc += sn[kk*8+2*q]*f.x + sn[kk*8+2*q+1]*f.y;
    }
  }
  qs[row*256+t]=acc;
}

// ---------------- fused attention: dots+softmax -> w -> partial agg (atomic) ----------------
__global__ __launch_bounds__(256) void k_att(const __half* __restrict__ x, const float* __restrict__ qs,
                                             float* __restrict__ aggF, float* __restrict__ wsumF){
  int b = blockIdx.x>>4;
  int t = threadIdx.x;
  size_t j = (size_t)blockIdx.x*256 + t;
  __shared__ __align__(16) float qt[256][8];
  __shared__ __align__(16) float wl[256][8];
  __shared__ __align__(16) float aggl[4][2048];
  __shared__ float wsl[4][8];
  const float* qb = qs + b*2048;
  for(int e=t;e<2048;e+=256) qt[e&255][e>>8]=qb[e];
  __syncthreads();
  const uint4* xr = (const uint4*)(x + j*DD);
  float pd[8]={0,0,0,0,0,0,0,0};
#pragma unroll 2
  for(int ch=0; ch<32; ch++){
    uint4 u = xr[ch];
    float2 f0=u2f2(u.x), f1=u2f2(u.y), f2=u2f2(u.z), f3=u2f2(u.w);
    float xv[8]={f0.x,f0.y,f1.x,f1.y,f2.x,f2.y,f3.x,f3.y};
    int c0=ch*8;
#pragma unroll
    for(int cc=0;cc<8;cc++){
      const float4* qp=(const float4*)&qt[c0+cc][0];
      float4 qa=qp[0], qc=qp[1];
      float xvv=xv[cc];
      pd[0]+=qa.x*xvv; pd[1]+=qa.y*xvv; pd[2]+=qa.z*xvv; pd[3]+=qa.w*xvv;
      pd[4]+=qc.x*xvv; pd[5]+=qc.y*xvv; pd[6]+=qc.z*xvv; pd[7]+=qc.w*xvv;
    }
  }
  float mx=pd[0];
#pragma unroll
  for(int i=1;i<8;i++) mx=fmaxf(mx,pd[i]);
  float ev[8]; float ssum=0.f;
#pragma unroll
  for(int i=0;i<8;i++){ ev[i]=__expf(pd[i]-mx); ssum+=ev[i]; }
  float inv=1.0f/ssum;
#pragma unroll
  for(int i=0;i<8;i++) wl[t][i]=ev[i]*inv+1e-5f;
  __syncthreads();
  int wid=t>>6, lane=t&63;
  float acc[8][4];
#pragma unroll
  for(int i=0;i<8;i++){ acc[i][0]=0;acc[i][1]=0;acc[i][2]=0;acc[i][3]=0; }
  float ws[8]={0,0,0,0,0,0,0,0};
  for(int r=0;r<64;r++){
    int jl = wid*64 + r;
    uint2 u = ((const uint2*)(x + ((size_t)blockIdx.x*256 + jl)*DD))[lane];
    float2 f01=u2f2(u.x), f23=u2f2(u.y);
    const float4* wp=(const float4*)&wl[jl][0];
    float4 wa=wp[0], wb_=wp[1];
    float wv[8]={wa.x,wa.y,wa.z,wa.w,wb_.x,wb_.y,wb_.z,wb_.w};
    float xv[4]={f01.x,f01.y,f23.x,f23.y};
#pragma unroll
    for(int i=0;i<8;i++){
      acc[i][0]+=wv[i]*xv[0]; acc[i][1]+=wv[i]*xv[1];
      acc[i][2]+=wv[i]*xv[2]; acc[i][3]+=wv[i]*xv[3];
      ws[i]+=wv[i];
    }
  }
#pragma unroll
  for(int i=0;i<8;i++){
    float4 st={acc[i][0],acc[i][1],acc[i][2],acc[i][3]};
    *((float4*)&aggl[wid][i*256 + lane*4])=st;
  }
  if(lane==0){
#pragma unroll
    for(int i=0;i<8;i++) wsl[wid][i]=ws[i];
  }
  __syncthreads();
  float* ab = aggF + (size_t)b*2048;
  for(int e=t;e<2048;e+=256)
    atomicAdd(&ab[e], aggl[0][e]+aggl[1][e]+aggl[2][e]+aggl[3][e]);
  if(t<8) atomicAdd(&wsumF[b*8+t], wsl[0][t]+wsl[1][t]+wsl[2][t]+wsl[3][t]);
}

// ---------------- t_all: cooperative tail = gates | gruln | mlp1 | mlp2p | fin ----------------
__global__ __launch_bounds__(256) void t_all(
    const float* __restrict__ aggF, const float* __restrict__ wsumF,
    const float* __restrict__ slots_in, const __half* __restrict__ slotsh_r,
    const __half* __restrict__ Wg,
    const float* __restrict__ bih, const float* __restrict__ bhh,
    const float* __restrict__ lm_g, const float* __restrict__ lm_b,
    const __half* __restrict__ W1t, const float* __restrict__ b1,
    const __half* __restrict__ W2t, const float* __restrict__ b2,
    const float* __restrict__ ls_g, const float* __restrict__ ls_b,
    const __half* __restrict__ M2h,
    float* __restrict__ gl, float* __restrict__ hb, __half* __restrict__ ysh,
    __half* __restrict__ z1h, float* __restrict__ pp,
    float* __restrict__ dst, __half* __restrict__ slotsh_w, float* __restrict__ qs,
    int last){
  cg::grid_group grid = cg::this_grid();
  const int blk=blockIdx.x, t=threadIdx.x, G=gridDim.x;
  const int lane=t&63, wid=t>>6;
  __shared__ __align__(16) char smem[52224];
  __shared__ float facS[32];
  __shared__ float redS[4], redQ[4];
  __shared__ __align__(16) float ysmall[256];

  // ======== Phase A: gates GEMM (384 virtual blocks; R11 t_gates body) ========
  for(int vb=blk; vb<384; vb+=G){
    __syncthreads();
    int rt=vb&15, ct=vb>>4;
    int r0=rt*32, c0=ct*64;
    float (*Af)[264] = (float(*)[264])smem;
    float (*Wf)[68]  = (float(*)[68])(smem + 33792);
    if(ct<12){
      if(t<32) facS[t]=4096.0f/wsumF[r0+t];
      __syncthreads();
#pragma unroll
      for(int q=0;q<8;q++){
        int u=q*256+t;
        int row=u>>6, c4=u&63;
        float4 v=((const float4*)(aggF+(size_t)(r0+row)*256))[c4];
        float f=facS[row];
        v.x*=f; v.y*=f; v.z*=f; v.w*=f;
        *(float4*)&Af[row][c4*4]=v;
      }
    } else {
#pragma unroll
      for(int q=0;q<4;q++){
        int u=q*256+t;
        int row=u>>5, kk=u&31;
        st8(&Af[row][kk*8], ((const uint4*)(slotsh_r + ((size_t)(r0+row))*256))[kk]);
      }
    }
    float acc[2][4]={{0,0,0,0},{0,0,0,0}};
    int tx=t&15, ty=t>>4;
    for(int kc=0;kc<4;kc++){
      __syncthreads();
#pragma unroll
      for(int q=0;q<2;q++){
        int u=q*256+t;
        int kk=u>>3, cb=u&7;
        st8(&Wf[kk][cb*8], ((const uint4*)(Wg + (size_t)(kc*64+kk)*1536 + c0))[cb]);
      }
      __syncthreads();
#pragma unroll
      for(int k4=0;k4<16;k4++){
        float4 a0=*(const float4*)&Af[ty][kc*64+k4*4];
        float4 a1=*(const float4*)&Af[ty+16][kc*64+k4*4];
        float av0[4]={a0.x,a0.y,a0.z,a0.w};
        float av1[4]={a1.x,a1.y,a1.z,a1.w};
#pragma unroll
        for(int jj=0;jj<4;jj++){
          float4 wv=*(const float4*)&Wf[k4*4+jj][tx*4];
          acc[0][0]+=av0[jj]*wv.x; acc[0][1]+=av0[jj]*wv.y; acc[0][2]+=av0[jj]*wv.z; acc[0][3]+=av0[jj]*wv.w;
          acc[1][0]+=av1[jj]*wv.x; acc[1][1]+=av1[jj]*wv.y; acc[1][2]+=av1[jj]*wv.z; acc[1][3]+=av1[jj]*wv.w;
        }
      }
    }
    int col=c0+tx*4;
    const float* bb=(ct<12)? bih : bhh;
    int bcol=(ct<12)? col : col-768;
    float4 bv=*(const float4*)&bb[bcol];
    float4 o0={acc[0][0]+bv.x, acc[0][1]+bv.y, acc[0][2]+bv.z, acc[0][3]+bv.w};
    float4 o1={acc[1][0]+bv.x, acc[1][1]+bv.y, acc[1][2]+bv.z, acc[1][3]+bv.w};
    *(float4*)&gl[(size_t)(r0+ty)*1536+col]=o0;
    *(float4*)&gl[(size_t)(r0+ty+16)*1536+col]=o1;
  }
  grid.sync();

  // ======== Phase B: GRU + MLP pre-norm (512 virtual rows) ========
  for(int row=blk; row<512; row+=G){
    __syncthreads();
    int c=t;
    const float* gr = gl + (size_t)row*1536;
    float gir=gr[c], giz=gr[256+c], gin=gr[512+c];
    float ghr=gr[768+c], ghz=gr[1024+c], ghn=gr[1280+c];
    float hp = slots_in[(size_t)row*256+c];
    float rr=sigm(gir+ghr), z=sigm(giz+ghz);
    float n=tanhf(gin+rr*ghn);
    float hv=(1.0f-z)*n+z*hp;
    hb[(size_t)row*256+c]=hv;
    float s=wredsum(hv), ss=wredsum(hv*hv);
    if(lane==0){ redS[wid]=s; redQ[wid]=ss; }
    __syncthreads();
    float S=redS[0]+redS[1]+redS[2]+redS[3];
    float SS=redQ[0]+redQ[1]+redQ[2]+redQ[3];
    float m=S*(1.0f/256.0f);
    float rs=rsqrtf(SS*(1.0f/256.0f)-m*m+1e-5f);
    ysh[(size_t)row*256+c]=__float2half((hv-m)*rs*lm_g[c]+lm_b[c]);
  }
  grid.sync();

  // ======== Phase C: mlp1 (256 virtual blocks; R11 t_mlp1 body) ========
  for(int vb=blk; vb<256; vb+=G){
    __syncthreads();
    int rt=vb&15, ct=vb>>4;
    int r0=rt*32, c0=ct*64;
    float (*Af)[264] = (float(*)[264])smem;
    float (*Wf)[68]  = (float(*)[68])(smem + 33792);
#pragma unroll
    for(int q=0;q<4;q++){
      int u=q*256+t; int row=u>>5, kk=u&31;
      st8(&Af[row][kk*8], ((const uint4*)(ysh + ((size_t)(r0+row))*256))[kk]);
    }
    float acc[2][4]={{0,0,0,0},{0,0,0,0}};
    int tx=t&15, ty=t>>4;
    for(int kc=0;kc<4;kc++){
      __syncthreads();
#pragma unroll
      for(int q=0;q<2;q++){
        int u=q*256+t; int kk=u>>3, cb=u&7;
        st8(&Wf[kk][cb*8], ((const uint4*)(W1t + (size_t)(kc*64+kk)*1024 + c0))[cb]);
      }
      __syncthreads();
#pragma unroll
      for(int k4=0;k4<16;k4++){
        float4 a0=*(const float4*)&Af[ty][kc*64+k4*4];
        float4 a1=*(const float4*)&Af[ty+16][kc*64+k4*4];
        float av0[4]={a0.x,a0.y,a0.z,a0.w};
        float av1[4]={a1.x,a1.y,a1.z,a1.w};
#pragma unroll
        for(int jj=0;jj<4;jj++){
          float4 wv=*(const float4*)&Wf[k4*4+jj][tx*4];
          acc[0][0]+=av0[jj]*wv.x; acc[0][1]+=av0[jj]*wv.y; acc[0][2]+=av0[jj]*wv.z; acc[0][3]+=av0[jj]*wv.w;
          acc[1][0]+=av1[jj]*wv.x; acc[1][1]+=av1[jj]*wv.y; acc[1][2]+=av1[jj]*wv.z; acc[1][3]+=av1[jj]*wv.w;
        }
      }
    }
    int col=c0+tx*4;
    float4 bv=*(const float4*)&b1[col];
#pragma unroll
    for(int rr2=0;rr2<2;rr2++){
      float v0=acc[rr2][0]+bv.x, v1=acc[rr2][1]+bv.y, v2=acc[rr2][2]+bv.z, v3=acc[rr2][3]+bv.w;
      v0=v0>0.f?v0:0.01f*v0; v1=v1>0.f?v1:0.01f*v1;
      v2=v2>0.f?v2:0.01f*v2; v3=v3>0.f?v3:0.01f*v3;
      __half2 p0=__floats2half2_rn(v0,v1), p1=__floats2half2_rn(v2,v3);
      uint2 u2; __builtin_memcpy(&u2.x,&p0,4); __builtin_memcpy(&u2.y,&p1,4);
      *(uint2*)&z1h[(size_t)(r0+ty+rr2*16)*1024+col]=u2;
    }
  }
  grid.sync();

  // ======== Phase D: mlp2 partials (512 virtual blocks; R11 t_mlp2p body) ========
  for(int vb=blk; vb<512; vb+=G){
    __syncthreads();
    int rt=vb&15, ct=(vb>>4)&3, kc=vb>>6;
    int r0=rt*32, c0=ct*64;
    float (*Af)[136] = (float(*)[136])smem;
    float (*Wf)[68]  = (float(*)[68])(smem + 17408);
#pragma unroll
    for(int q=0;q<2;q++){
      int u=q*256+t;
      int row=u>>4, seg=u&15;
      st8(&Af[row][seg*8], ((const uint4*)(z1h + (size_t)(r0+row)*1024 + kc*128))[seg]);
    }
#pragma unroll
    for(int q=0;q<4;q++){
      int u=q*256+t;
      int kk=u>>3, cb=u&7;
      st8(&Wf[kk][cb*8], ((const uint4*)(W2t + (size_t)(kc*128+kk)*256 + c0))[cb]);
    }
    __syncthreads();
    float acc[2][4]={{0,0,0,0},{0,0,0,0}};
    int tx=t&15, ty=t>>4;
#pragma unroll
    for(int k4=0;k4<32;k4++){
      float4 a0=*(const float4*)&Af[ty][k4*4];
      float4 a1=*(const float4*)&Af[ty+16][k4*4];
      float av0[4]={a0.x,a0.y,a0.z,a0.w};
      float av1[4]={a1.x,a1.y,a1.z,a1.w};
#pragma unroll
      for(int jj=0;jj<4;jj++){
        float4 wv=*(const float4*)&Wf[k4*4+jj][tx*4];
        acc[0][0]+=av0[jj]*wv.x; acc[0][1]+=av0[jj]*wv.y; acc[0][2]+=av0[jj]*wv.z; acc[0][3]+=av0[jj]*wv.w;
        acc[1][0]+=av1[jj]*wv.x; acc[1][1]+=av1[jj]*wv.y; acc[1][2]+=av1[jj]*wv.z; acc[1][3]+=av1[jj]*wv.w;
      }
    }
    int col=c0+tx*4;
    float4 o0={acc[0][0],acc[0][1],acc[0][2],acc[0][3]};
    float4 o1={acc[1][0],acc[1][1],acc[1][2],acc[1][3]};
    *(float4*)&pp[((size_t)kc*512 + r0+ty)*256+col]=o0;
    *(float4*)&pp[((size_t)kc*512 + r0+ty+16)*256+col]=o1;
  }
  grid.sync();

  // ======== Phase E: reduce + residual; slot-LN + qs (512 virtual rows) ========
  for(int row=blk; row<512; row+=G){
    __syncthreads();
    int c=t;
    float s = hb[(size_t)row*256+c] + b2[c];
#pragma unroll
    for(int kc=0;kc<8;kc++) s += pp[((size_t)kc*512+row)*256+c];
    dst[(size_t)row*256+c]=s;
    if(!last){
      slotsh_w[(size_t)row*256+c]=__float2half(s);
      float su=wredsum(s), sq=wredsum(s*s);
      if(lane==0){ redS[wid]=su; redQ[wid]=sq; }
      __syncthreads();
      float S=redS[0]+redS[1]+redS[2]+redS[3];
      float SS=redQ[0]+redQ[1]+redQ[2]+redQ[3];
      float m=S*(1.0f/256.0f);
      float rs=rsqrtf(SS*(1.0f/256.0f)-m*m+1e-5f);
      ysmall[c]=(s-m)*rs*ls_g[c]+ls_b[c];
      __syncthreads();
      const uint4* m4=(const uint4*)(M2h+(size_t)c*256);
      float acc=0.f;
#pragma unroll 4
      for(int kk=0;kk<32;kk++){
        U4 w; w.u=m4[kk];
#pragma unroll
        for(int q=0;q<4;q++){
          float2 f=__half22float2(w.h[q]);
          acc += ysmall[kk*8+2*q]*f.x + ysmall[kk*8+2*q+1]*f.y;
        }
      }
      qs[(size_t)row*256+c]=acc;
    }
  }
}

extern "C" void kernel_launch(void* const* d_in, const int* in_sizes, int n_in,
                              void* d_out, int out_size, void* d_ws, size_t ws_size,
                              hipStream_t stream){
  const float* inputs=(const float*)d_in[0];
  const float* sinit =(const float*)d_in[1];
  const float* Wq =(const float*)d_in[2];
  const float* Wk =(const float*)d_in[3];
  const float* Wv =(const float*)d_in[4];
  const float* Wih=(const float*)d_in[5];
  const float* Whh=(const float*)d_in[6];
  const float* bih=(const float*)d_in[7];
  const float* bhh=(const float*)d_in[8];
  const float* lin_g=(const float*)d_in[9];
  const float* lin_b=(const float*)d_in[10];
  const float* ls_g=(const float*)d_in[11];
  const float* ls_b=(const float*)d_in[12];
  const float* lm_g=(const float*)d_in[13];
  const float* lm_b=(const float*)d_in[14];
  const float* W1=(const float*)d_in[15];
  const float* b1=(const float*)d_in[16];
  const float* W2=(const float*)d_in[17];
  const float* b2=(const float*)d_in[18];

  char* w=(char*)d_ws;
  __half* x    =(__half*)w; w += (size_t)BB*NN*DD*2;        // 134.2 MB
  float* qs    =(float*)w;  w += 512*256*4;
  float* slots =(float*)w;  w += 512*256*4;
  __half* slotsh=(__half*)w; w += 512*256*2;
  __half* M2h  =(__half*)w; w += 256*256*2;
  __half* Wg   =(__half*)w; w += 256*1536*2;
  __half* W1t  =(__half*)w; w += 256*1024*2;
  __half* W2t  =(__half*)w; w += 1024*256*2;
  float* hb    =(float*)w;  w += 512*256*4;
  __half* ysh  =(__half*)w; w += 512*256*2;
  __half* z1h  =(__half*)w; w += (size_t)512*1024*2;
  float* pp    =(float*)w;  w += (size_t)8*512*256*4;       // 4.2 MB
  float* gl_   =(float*)w;  w += (size_t)512*1536*4;        // 3.1 MB
  float* aggZ  =(float*)w;  w += (size_t)(3*512*256 + 3*512)*4;

  float* aggFv[3]; float* wsumFv[3];
  for(int i=0;i<3;i++){ aggFv[i]=aggZ + (size_t)i*512*256; wsumFv[i]=aggZ + (size_t)3*512*256 + (size_t)i*512; }

  hipLaunchKernelGGL(kp_all, dim3(4230), dim3(256), 0, stream,
                     Whh, W1, W2, sinit, Wih, Wv, Wq, Wk,
                     Wg, W1t, W2t, slots, M2h, aggZ);
  hipLaunchKernelGGL(k_ln_x, dim3(65536),dim3(256), 0, stream, inputs, lin_g, lin_b, x);
  hipLaunchKernelGGL(k_pre,  dim3(512),  dim3(256), 0, stream, slots, ls_g, ls_b, M2h, qs, slotsh);

  int nb=0;
  hipError_t e = hipOccupancyMaxActiveBlocksPerMultiprocessor(&nb, t_all, 256, 0);
  if(e!=hipSuccess || nb<1) nb=1;
  int gridN = nb*256; if(gridN>384) gridN=384;

  for(int it=0; it<NITER; ++it){
    int last = (it==NITER-1);
    float* dst = last ? (float*)d_out : slots;
    hipLaunchKernelGGL(k_att, dim3(1024), dim3(256), 0, stream, x, qs, aggFv[it], wsumFv[it]);
    const float* aggC=aggFv[it]; const float* wsumC=wsumFv[it];
    const float* slotsC=slots; const __half* slotshC=slotsh;
    const __half* WgC=Wg; const __half* W1C=W1t; const __half* W2C=W2t; const __half* MC=M2h;
    float* glP=gl_; float* hbP=hb; __half* yshP=ysh; __half* z1P=z1h; float* ppP=pp;
    __half* slotshW=slotsh; float* qsP=qs;
    void* args[] = {
      (void*)&aggC, (void*)&wsumC, (void*)&slotsC, (void*)&slotshC, (void*)&WgC,
      (void*)&bih, (void*)&bhh, (void*)&lm_g, (void*)&lm_b,
      (void*)&W1C, (void*)&b1, (void*)&W2C, (void*)&b2,
      (void*)&ls_g, (void*)&ls_b, (void*)&MC,
      (void*)&glP, (void*)&hbP, (void*)&yshP, (void*)&z1P, (void*)&ppP,
      (void*)&dst, (void*)&slotshW, (void*)&qsP, (void*)&last
    };
    hipLaunchCooperativeKernel((void*)t_all, dim3(gridN), dim3(256), args, 0, stream);
  }
}

// Round 14
// 582.669 us; speedup vs baseline: 1.4349x; 1.4349x over previous
//
#include <hip/hip_runtime.h>
#include <hip/hip_fp16.h>
#include <hip/hip_bf16.h>

// SlotAttention restructured:
//  dots = qs . x   with qs = LN(slots) @ (scale * Wq^T Wk)   (K never materialized)
//  updates folded:  gates_ih = (agg*fac) @ (Wih@Wv)^T        (V and upd never materialized)
// x = LN(inputs) fp16. fp32 accumulation. Output fp32.
// R13 (coop, regressed): grid.sync ~35us each on MI355X -> banned.
// R14 = R11 base, tail 5 -> 3 dispatches/iter:
//  - t_gruln folded into t_mlp1g (each block recomputes GRU+LN for its 32 rows
//    into its LDS A-tile; ct==0 writes hb; ys stays fp32)
//  - t_fin folded into t_mlp2f via o2 atomicAdd + last-block-reduce per row-tile
//    (device-scope counter, __threadfence; o2/cnt zeroed every call by kp_all)

#define BB 64
#define NN 4096
#define DD 256
#define NSL 8
#define NITER 3

__device__ __forceinline__ float wredsum(float v){
#pragma unroll
  for(int m=32;m;m>>=1) v += __shfl_xor(v, m, 64);
  return v;
}
__device__ __forceinline__ float2 u2f2(unsigned u){ __half2 h; __builtin_memcpy(&h,&u,4); return __half22float2(h); }
__device__ __forceinline__ float sigm(float v){ return 1.0f/(1.0f+__expf(-v)); }

union U4 { uint4 u; __half2 h[4]; };

__device__ __forceinline__ void st8(float* dst, uint4 uu){
  U4 v; v.u=uu;
  float2 f0=__half22float2(v.h[0]), f1=__half22float2(v.h[1]),
         f2=__half22float2(v.h[2]), f3=__half22float2(v.h[3]);
  dst[0]=f0.x; dst[1]=f0.y; dst[2]=f1.x; dst[3]=f1.y;
  dst[4]=f2.x; dst[5]=f2.y; dst[6]=f3.x; dst[7]=f3.y;
}

#define F8(a,b,nm) float nm[8]={a.x,a.y,a.z,a.w,b.x,b.y,b.z,b.w}

// ---------------- merged prep: weights + slots + WC GEMM + M GEMM + zero aggF/wsumF/o2/cnt ----------------
__global__ __launch_bounds__(256) void kp_all(
    const float* __restrict__ Whh, const float* __restrict__ W1,
    const float* __restrict__ W2,  const float* __restrict__ sinit,
    const float* __restrict__ Wih, const float* __restrict__ Wv,
    const float* __restrict__ Wq,  const float* __restrict__ Wk,
    __half* __restrict__ Wg, __half* __restrict__ W1t, __half* __restrict__ W2t,
    float* __restrict__ slots, __half* __restrict__ M2h, float* __restrict__ zbuf){
  int bid=blockIdx.x, t=threadIdx.x;
  if(bid<1664){
    for(int idx=bid*256+t; idx<851968; idx+=1664*256){
      if(idx<196608){ int col=idx>>8, c=idx&255; Wg[(size_t)c*1536+768+col]=__float2half(Whh[idx]); }
      else if(idx<458752){ int k=idx-196608; int col=k>>8, c=k&255; W1t[(size_t)c*1024+col]=__float2half(W1[k]); }
      else if(idx<720896){ int k=idx-458752; int col=k>>10, c=k&1023; W2t[(size_t)c*256+col]=__float2half(W2[k]); }
      else { int k=idx-720896; slots[k]=sinit[k&2047]; }
    }
  } else if(bid<2432){
    int col=bid-1664;            // 0..767
    __shared__ float wr[256];
    wr[t]=Wih[col*256+t];
    __syncthreads();
    float acc=0.f;
#pragma unroll 8
    for(int d=0;d<256;d++) acc += wr[d]*Wv[d*256+t];
    Wg[(size_t)t*1536+col]=__float2half(acc);
  } else if(bid<2688){
    int c=bid-2432;              // 0..255
    float acc=0.f;
#pragma unroll 8
    for(int d=0;d<256;d++) acc += Wq[d*256+t]*Wk[d*256+c];
    M2h[(size_t)c*256+t]=__float2half(acc*0.0625f);
  } else {
    int idx=(bid-2688)*256+t;
    if(idx<788160) zbuf[idx]=0.f;
  }
}

// ---------------- x = LN(inputs) -> fp16 ----------------
__global__ __launch_bounds__(256) void k_ln_x(const float* __restrict__ in, const float* __restrict__ g,
                                              const float* __restrict__ bbv, __half* __restrict__ x){
  int row  = blockIdx.x*4 + (threadIdx.x>>6);
  int lane = threadIdx.x&63;
  const float4 v = ((const float4*)(in + (size_t)row*DD))[lane];
  float s  = v.x+v.y+v.z+v.w;
  float ss = v.x*v.x+v.y*v.y+v.z*v.z+v.w*v.w;
  s = wredsum(s); ss = wredsum(ss);
  float m = s*(1.0f/256.0f);
  float r = rsqrtf(ss*(1.0f/256.0f) - m*m + 1e-5f);
  float4 gv = ((const float4*)g)[lane];
  float4 bv = ((const float4*)bbv)[lane];
  float y0=(v.x-m)*r*gv.x+bv.x, y1=(v.y-m)*r*gv.y+bv.y;
  float y2=(v.z-m)*r*gv.z+bv.z, y3=(v.w-m)*r*gv.w+bv.w;
  __half2 h0=__floats2half2_rn(y0,y1), h1=__floats2half2_rn(y2,y3);
  uint2 u; __builtin_memcpy(&u.x,&h0,4); __builtin_memcpy(&u.y,&h1,4);
  ((uint2*)(x + (size_t)row*DD))[lane] = u;
}

// ---------------- initial qs = LN(slots) @ M (once); also writes slotsh ----------------
__global__ __launch_bounds__(256) void k_pre(const float* __restrict__ slots, const float* __restrict__ g,
                                             const float* __restrict__ bbv, const __half* __restrict__ M2h,
                                             float* __restrict__ qs, __half* __restrict__ slotsh){
  int row = blockIdx.x;      // 0..511
  int t = threadIdx.x;
  __shared__ __align__(16) float sn[256];
  __shared__ float red[8];
  float v = slots[row*256 + t];
  slotsh[(size_t)row*256+t]=__float2half(v);
  float s = wredsum(v), ss = wredsum(v*v);
  int wid=t>>6, lane=t&63;
  if(lane==0){ red[wid]=s; red[4+wid]=ss; }
  __syncthreads();
  float S  = red[0]+red[1]+red[2]+red[3];
  float SS = red[4]+red[5]+red[6]+red[7];
  float m = S*(1.0f/256.0f);
  float r = rsqrtf(SS*(1.0f/256.0f) - m*m + 1e-5f);
  sn[t] = (v-m)*r*g[t]+bbv[t];
  __syncthreads();
  const uint4* w4 = (const uint4*)(M2h + (size_t)t*256);
  float acc=0.f;
#pragma unroll 4
  for(int kk=0;kk<32;kk++){
    U4 w; w.u=w4[kk];
#pragma unroll
    for(int q=0;q<4;q++){
      float2 f=__half22float2(w.h[q]);
      acc += sn[kk*8+2*q]*f.x + sn[kk*8+2*q+1]*f.y;
    }
  }
  qs[row*256+t]=acc;
}

// ---------------- fused attention: dots+softmax -> w -> partial agg (atomic) ----------------
__global__ __launch_bounds__(256) void k_att(const __half* __restrict__ x, const float* __restrict__ qs,
                                             float* __restrict__ aggF, float* __restrict__ wsumF){
  int b = blockIdx.x>>4;
  int t = threadIdx.x;
  size_t j = (size_t)blockIdx.x*256 + t;
  __shared__ __align__(16) float qt[256][8];
  __shared__ __align__(16) float wl[256][8];
  __shared__ __align__(16) float aggl[4][2048];
  __shared__ float wsl[4][8];
  const float* qb = qs + b*2048;
  for(int e=t;e<2048;e+=256) qt[e&255][e>>8]=qb[e];
  __syncthreads();
  const uint4* xr = (const uint4*)(x + j*DD);
  float pd[8]={0,0,0,0,0,0,0,0};
#pragma unroll 2
  for(int ch=0; ch<32; ch++){
    uint4 u = xr[ch];
    float2 f0=u2f2(u.x), f1=u2f2(u.y), f2=u2f2(u.z), f3=u2f2(u.w);
    float xv[8]={f0.x,f0.y,f1.x,f1.y,f2.x,f2.y,f3.x,f3.y};
    int c0=ch*8;
#pragma unroll
    for(int cc=0;cc<8;cc++){
      const float4* qp=(const float4*)&qt[c0+cc][0];
      float4 qa=qp[0], qc=qp[1];
      float xvv=xv[cc];
      pd[0]+=qa.x*xvv; pd[1]+=qa.y*xvv; pd[2]+=qa.z*xvv; pd[3]+=qa.w*xvv;
      pd[4]+=qc.x*xvv; pd[5]+=qc.y*xvv; pd[6]+=qc.z*xvv; pd[7]+=qc.w*xvv;
    }
  }
  float mx=pd[0];
#pragma unroll
  for(int i=1;i<8;i++) mx=fmaxf(mx,pd[i]);
  float ev[8]; float ssum=0.f;
#pragma unroll
  for(int i=0;i<8;i++){ ev[i]=__expf(pd[i]-mx); ssum+=ev[i]; }
  float inv=1.0f/ssum;
#pragma unroll
  for(int i=0;i<8;i++) wl[t][i]=ev[i]*inv+1e-5f;
  __syncthreads();
  int wid=t>>6, lane=t&63;
  float acc[8][4];
#pragma unroll
  for(int i=0;i<8;i++){ acc[i][0]=0;acc[i][1]=0;acc[i][2]=0;acc[i][3]=0; }
  float ws[8]={0,0,0,0,0,0,0,0};
  for(int r=0;r<64;r++){
    int jl = wid*64 + r;
    uint2 u = ((const uint2*)(x + ((size_t)blockIdx.x*256 + jl)*DD))[lane];
    float2 f01=u2f2(u.x), f23=u2f2(u.y);
    const float4* wp=(const float4*)&wl[jl][0];
    float4 wa=wp[0], wb_=wp[1];
    float wv[8]={wa.x,wa.y,wa.z,wa.w,wb_.x,wb_.y,wb_.z,wb_.w};
    float xv[4]={f01.x,f01.y,f23.x,f23.y};
#pragma unroll
    for(int i=0;i<8;i++){
      acc[i][0]+=wv[i]*xv[0]; acc[i][1]+=wv[i]*xv[1];
      acc[i][2]+=wv[i]*xv[2]; acc[i][3]+=wv[i]*xv[3];
      ws[i]+=wv[i];
    }
  }
#pragma unroll
  for(int i=0;i<8;i++){
    float4 st={acc[i][0],acc[i][1],acc[i][2],acc[i][3]};
    *((float4*)&aggl[wid][i*256 + lane*4])=st;
  }
  if(lane==0){
#pragma unroll
    for(int i=0;i<8;i++) wsl[wid][i]=ws[i];
  }
  __syncthreads();
  float* ab = aggF + (size_t)b*2048;
  for(int e=t;e<2048;e+=256)
    atomicAdd(&ab[e], aggl[0][e]+aggl[1][e]+aggl[2][e]+aggl[3][e]);
  if(t<8) atomicAdd(&wsumF[b*8+t], wsl[0][t]+wsl[1][t]+wsl[2][t]+wsl[3][t]);
}

// ---------------- t_gates: gl[512][1536] = [(agg*fac)@WC^T+bih | slotsh@Whh^T+bhh] ----------------
__global__ __launch_bounds__(256) void t_gates(const float* __restrict__ aggF,
    const float* __restrict__ wsumF,
    const __half* __restrict__ slotsh, const __half* __restrict__ Wg,
    const float* __restrict__ bih, const float* __restrict__ bhh,
    float* __restrict__ gl){
  int rt=blockIdx.x&15, ct=blockIdx.x>>4;
  int t=threadIdx.x;
  int r0=rt*32, c0=ct*64;
  __shared__ __align__(16) float Af[32][264];
  __shared__ __align__(16) float Wf[64][68];
  __shared__ float facS[32];
  if(ct<12){
    if(t<32) facS[t]=4096.0f/wsumF[r0+t];
    __syncthreads();
#pragma unroll
    for(int q=0;q<8;q++){
      int u=q*256+t;
      int row=u>>6, c4=u&63;
      float4 v=((const float4*)(aggF+(size_t)(r0+row)*256))[c4];
      float f=facS[row];
      v.x*=f; v.y*=f; v.z*=f; v.w*=f;
      *(float4*)&Af[row][c4*4]=v;
    }
  } else {
#pragma unroll
    for(int q=0;q<4;q++){
      int u=q*256+t;
      int row=u>>5, kk=u&31;
      st8(&Af[row][kk*8], ((const uint4*)(slotsh + ((size_t)(r0+row))*256))[kk]);
    }
  }
  float acc[2][4]={{0,0,0,0},{0,0,0,0}};
  int tx=t&15, ty=t>>4;
  for(int kc=0;kc<4;kc++){
    __syncthreads();
#pragma unroll
    for(int q=0;q<2;q++){
      int u=q*256+t;
      int kk=u>>3, cb=u&7;
      st8(&Wf[kk][cb*8], ((const uint4*)(Wg + (size_t)(kc*64+kk)*1536 + c0))[cb]);
    }
    __syncthreads();
#pragma unroll
    for(int k4=0;k4<16;k4++){
      float4 a0=*(const float4*)&Af[ty][kc*64+k4*4];
      float4 a1=*(const float4*)&Af[ty+16][kc*64+k4*4];
      float av0[4]={a0.x,a0.y,a0.z,a0.w};
      float av1[4]={a1.x,a1.y,a1.z,a1.w};
#pragma unroll
      for(int jj=0;jj<4;jj++){
        float4 wv=*(const float4*)&Wf[k4*4+jj][tx*4];
        acc[0][0]+=av0[jj]*wv.x; acc[0][1]+=av0[jj]*wv.y; acc[0][2]+=av0[jj]*wv.z; acc[0][3]+=av0[jj]*wv.w;
        acc[1][0]+=av1[jj]*wv.x; acc[1][1]+=av1[jj]*wv.y; acc[1][2]+=av1[jj]*wv.z; acc[1][3]+=av1[jj]*wv.w;
      }
    }
  }
  int col=c0+tx*4;
  const float* bb=(ct<12)? bih : bhh;
  int bcol=(ct<12)? col : col-768;
  float4 bv=*(const float4*)&bb[bcol];
  float4 o0={acc[0][0]+bv.x, acc[0][1]+bv.y, acc[0][2]+bv.z, acc[0][3]+bv.w};
  float4 o1={acc[1][0]+bv.x, acc[1][1]+bv.y, acc[1][2]+bv.z, acc[1][3]+bv.w};
  *(float4*)&gl[(size_t)(r0+ty)*1536+col]=o0;
  *(float4*)&gl[(size_t)(r0+ty+16)*1536+col]=o1;
}

// ---------------- t_mlp1g: GRU+LN (recomputed per block) + mlp1 GEMM -> z1h ----------------
// grid 256 = 16 rt x 16 ct, 256 thr
__global__ __launch_bounds__(256) void t_mlp1g(const float* __restrict__ gl,
    const float* __restrict__ slots,
    const float* __restrict__ lm_g, const float* __restrict__ lm_b,
    const __half* __restrict__ W1t, const float* __restrict__ b1,
    float* __restrict__ hb, __half* __restrict__ z1h){
  int rt=blockIdx.x&15, ct=blockIdx.x>>4;
  int t=threadIdx.x;
  int r0=rt*32, c0=ct*64;
  __shared__ __align__(16) float Af[32][264];
  __shared__ __align__(16) float Wf[64][68];
  // GRU + LN into Af (ys fp32)
  int lane32=t&31, rowg=t>>5;
#pragma unroll
  for(int p=0;p<4;p++){
    int row=p*8+rowg, gr=r0+row, c8=lane32*8;
    const float* g=gl+(size_t)gr*1536;
    float4 A0=*(const float4*)&g[c8],      A1=*(const float4*)&g[c8+4];      F8(A0,A1,gi);
    float4 B0=*(const float4*)&g[256+c8],  B1=*(const float4*)&g[256+c8+4];  F8(B0,B1,gz);
    float4 C0=*(const float4*)&g[512+c8],  C1=*(const float4*)&g[512+c8+4];  F8(C0,C1,gn);
    float4 D0=*(const float4*)&g[768+c8],  D1=*(const float4*)&g[768+c8+4];  F8(D0,D1,hr);
    float4 E0=*(const float4*)&g[1024+c8], E1=*(const float4*)&g[1024+c8+4]; F8(E0,E1,hz);
    float4 G0=*(const float4*)&g[1280+c8], G1=*(const float4*)&g[1280+c8+4]; F8(G0,G1,hn);
    float4 H0=*(const float4*)&slots[(size_t)gr*256+c8];
    float4 H1=*(const float4*)&slots[(size_t)gr*256+c8+4]; F8(H0,H1,hp);
    float hv8[8]; float s=0.f,qq=0.f;
#pragma unroll
    for(int k=0;k<8;k++){
      float rr=sigm(gi[k]+hr[k]), zz=sigm(gz[k]+hz[k]);
      float nn=tanhf(gn[k]+rr*hn[k]);
      float hv=(1.0f-zz)*nn+zz*hp[k];
      hv8[k]=hv; s+=hv; qq+=hv*hv;
    }
#pragma unroll
    for(int m=16;m;m>>=1){ s+=__shfl_xor(s,m,64); qq+=__shfl_xor(qq,m,64); }
    float mean=s*(1.0f/256.0f);
    float rs=rsqrtf(qq*(1.0f/256.0f)-mean*mean+1e-5f);
    float4 L0=*(const float4*)&lm_g[c8], L1=*(const float4*)&lm_g[c8+4]; F8(L0,L1,lg);
    float4 M0=*(const float4*)&lm_b[c8], M1=*(const float4*)&lm_b[c8+4]; F8(M0,M1,lb);
#pragma unroll
    for(int k=0;k<8;k++) Af[row][c8+k]=(hv8[k]-mean)*rs*lg[k]+lb[k];
    if(ct==0){
      float4 o0={hv8[0],hv8[1],hv8[2],hv8[3]}, o1={hv8[4],hv8[5],hv8[6],hv8[7]};
      *(float4*)&hb[(size_t)gr*256+c8]=o0;
      *(float4*)&hb[(size_t)gr*256+c8+4]=o1;
    }
  }
  // mlp1 GEMM
  float acc[2][4]={{0,0,0,0},{0,0,0,0}};
  int tx=t&15, ty=t>>4;
  for(int kc=0;kc<4;kc++){
    __syncthreads();
#pragma unroll
    for(int q=0;q<2;q++){
      int u=q*256+t; int kk=u>>3, cb=u&7;
      st8(&Wf[kk][cb*8], ((const uint4*)(W1t + (size_t)(kc*64+kk)*1024 + c0))[cb]);
    }
    __syncthreads();
#pragma unroll
    for(int k4=0;k4<16;k4++){
      float4 a0=*(const float4*)&Af[ty][kc*64+k4*4];
      float4 a1=*(const float4*)&Af[ty+16][kc*64+k4*4];
      float av0[4]={a0.x,a0.y,a0.z,a0.w};
      float av1[4]={a1.x,a1.y,a1.z,a1.w};
#pragma unroll
      for(int jj=0;jj<4;jj++){
        float4 wv=*(const float4*)&Wf[k4*4+jj][tx*4];
        acc[0][0]+=av0[jj]*wv.x; acc[0][1]+=av0[jj]*wv.y; acc[0][2]+=av0[jj]*wv.z; acc[0][3]+=av0[jj]*wv.w;
        acc[1][0]+=av1[jj]*wv.x; acc[1][1]+=av1[jj]*wv.y; acc[1][2]+=av1[jj]*wv.z; acc[1][3]+=av1[jj]*wv.w;
      }
    }
  }
  int col=c0+tx*4;
  float4 bv=*(const float4*)&b1[col];
#pragma unroll
  for(int rr2=0;rr2<2;rr2++){
    float v0=acc[rr2][0]+bv.x, v1=acc[rr2][1]+bv.y, v2=acc[rr2][2]+bv.z, v3=acc[rr2][3]+bv.w;
    v0=v0>0.f?v0:0.01f*v0; v1=v1>0.f?v1:0.01f*v1;
    v2=v2>0.f?v2:0.01f*v2; v3=v3>0.f?v3:0.01f*v3;
    __half2 p0=__floats2half2_rn(v0,v1), p1=__floats2half2_rn(v2,v3);
    uint2 u2; __builtin_memcpy(&u2.x,&p0,4); __builtin_memcpy(&u2.y,&p1,4);
    *(uint2*)&z1h[(size_t)(r0+ty+rr2*16)*1024+col]=u2;
  }
}

// ---------------- t_mlp2f: mlp2 partial (atomic o2) + last-block fin (residual+LN+qs) ----------------
// grid 512 = 16 rt x 4 ct x 8 kc, 256 thr
__global__ __launch_bounds__(256) void t_mlp2f(const __half* __restrict__ z1h,
    const __half* __restrict__ W2t, const float* __restrict__ hb,
    const float* __restrict__ b2, const float* __restrict__ ls_g, const float* __restrict__ ls_b,
    const __half* __restrict__ M2h,
    float* __restrict__ o2, int* __restrict__ cnt,
    float* __restrict__ dst, __half* __restrict__ slotsh_w, float* __restrict__ qs, int last){
  int bidx=blockIdx.x;
  int rt=bidx&15, ct=(bidx>>4)&3, kc=bidx>>6;
  int t=threadIdx.x;
  int r0=rt*32, c0=ct*64;
  __shared__ __align__(16) char smem[52224];
  __shared__ int lastFlag;
  float (*Af)[136] = (float(*)[136])smem;
  float (*Wf)[68]  = (float(*)[68])(smem + 17408);
#pragma unroll
  for(int q=0;q<2;q++){
    int u=q*256+t;
    int row=u>>4, seg=u&15;
    st8(&Af[row][seg*8], ((const uint4*)(z1h + (size_t)(r0+row)*1024 + kc*128))[seg]);
  }
#pragma unroll
  for(int q=0;q<4;q++){
    int u=q*256+t;
    int kk=u>>3, cb=u&7;
    st8(&Wf[kk][cb*8], ((const uint4*)(W2t + (size_t)(kc*128+kk)*256 + c0))[cb]);
  }
  __syncthreads();
  float acc[2][4]={{0,0,0,0},{0,0,0,0}};
  int tx=t&15, ty=t>>4;
#pragma unroll
  for(int k4=0;k4<32;k4++){
    float4 a0=*(const float4*)&Af[ty][k4*4];
    float4 a1=*(const float4*)&Af[ty+16][k4*4];
    float av0[4]={a0.x,a0.y,a0.z,a0.w};
    float av1[4]={a1.x,a1.y,a1.z,a1.w};
#pragma unroll
    for(int jj=0;jj<4;jj++){
      float4 wv=*(const float4*)&Wf[k4*4+jj][tx*4];
      acc[0][0]+=av0[jj]*wv.x; acc[0][1]+=av0[jj]*wv.y; acc[0][2]+=av0[jj]*wv.z; acc[0][3]+=av0[jj]*wv.w;
      acc[1][0]+=av1[jj]*wv.x; acc[1][1]+=av1[jj]*wv.y; acc[1][2]+=av1[jj]*wv.z; acc[1][3]+=av1[jj]*wv.w;
    }
  }
  {
    int col=c0+tx*4;
    float* p0=&o2[(size_t)(r0+ty)*256+col];
    float* p1=&o2[(size_t)(r0+ty+16)*256+col];
    atomicAdd(p0+0,acc[0][0]); atomicAdd(p0+1,acc[0][1]); atomicAdd(p0+2,acc[0][2]); atomicAdd(p0+3,acc[0][3]);
    atomicAdd(p1+0,acc[1][0]); atomicAdd(p1+1,acc[1][1]); atomicAdd(p1+2,acc[1][2]); atomicAdd(p1+3,acc[1][3]);
  }
  __threadfence();
  if(t==0){ int old=atomicAdd(&cnt[rt],1); lastFlag=(old==31)?1:0; }
  __syncthreads();
  if(!lastFlag) return;
  __threadfence();
  // ---- FIN for rows r0..r0+31 ----
  float* ysl = (float*)smem;   // [32][256] = 32 KB (Af/Wf dead)
  int lane32=t&31, rowg=t>>5;
#pragma unroll
  for(int p=0;p<4;p++){
    int row=p*8+rowg, gr=r0+row, c8=lane32*8;
    float4 Hh0=*(const float4*)&hb[(size_t)gr*256+c8];
    float4 Hh1=*(const float4*)&hb[(size_t)gr*256+c8+4]; F8(Hh0,Hh1,hbv);
    float4 O0=*(const float4*)&o2[(size_t)gr*256+c8];
    float4 O1=*(const float4*)&o2[(size_t)gr*256+c8+4]; F8(O0,O1,ov);
    float4 B0=*(const float4*)&b2[c8], B1=*(const float4*)&b2[c8+4]; F8(B0,B1,bv);
    float sv8[8]; float s=0.f,qq=0.f;
#pragma unroll
    for(int k=0;k<8;k++){
      float sv=hbv[k]+ov[k]+bv[k];
      sv8[k]=sv; s+=sv; qq+=sv*sv;
    }
    float4 s0={sv8[0],sv8[1],sv8[2],sv8[3]}, s1={sv8[4],sv8[5],sv8[6],sv8[7]};
    *(float4*)&dst[(size_t)gr*256+c8]=s0;
    *(float4*)&dst[(size_t)gr*256+c8+4]=s1;
    if(!last){
      __half2 q0=__floats2half2_rn(sv8[0],sv8[1]), q1=__floats2half2_rn(sv8[2],sv8[3]);
      __half2 q2=__floats2half2_rn(sv8[4],sv8[5]), q3=__floats2half2_rn(sv8[6],sv8[7]);
      uint4 hu; __builtin_memcpy(&hu.x,&q0,4); __builtin_memcpy(&hu.y,&q1,4);
      __builtin_memcpy(&hu.z,&q2,4); __builtin_memcpy(&hu.w,&q3,4);
      *(uint4*)&slotsh_w[(size_t)gr*256+c8]=hu;
#pragma unroll
      for(int m=16;m;m>>=1){ s+=__shfl_xor(s,m,64); qq+=__shfl_xor(qq,m,64); }
      float mean=s*(1.0f/256.0f);
      float rs=rsqrtf(qq*(1.0f/256.0f)-mean*mean+1e-5f);
      float4 L0=*(const float4*)&ls_g[c8], L1=*(const float4*)&ls_g[c8+4]; F8(L0,L1,lg);
      float4 M0=*(const float4*)&ls_b[c8], M1=*(const float4*)&ls_b[c8+4]; F8(M0,M1,lb);
#pragma unroll
      for(int k=0;k<8;k++) ysl[row*256+c8+k]=(sv8[k]-mean)*rs*lg[k]+lb[k];
    }
  }
  if(last) return;
  __syncthreads();
  // qs for 32 rows: thread t = output col, M2h row reused across all rows
  {
    float acc2[32];
#pragma unroll
    for(int r=0;r<32;r++) acc2[r]=0.f;
    const uint4* m4=(const uint4*)(M2h+(size_t)t*256);
    for(int kk=0;kk<32;kk++){
      U4 w; w.u=m4[kk];
      float2 f0=__half22float2(w.h[0]), f1=__half22float2(w.h[1]);
      float2 f2=__half22float2(w.h[2]), f3=__half22float2(w.h[3]);
      float w8[8]={f0.x,f0.y,f1.x,f1.y,f2.x,f2.y,f3.x,f3.y};
#pragma unroll
      for(int r=0;r<32;r++){
        const float* yr=&ysl[r*256+kk*8];
        acc2[r]+=w8[0]*yr[0]+w8[1]*yr[1]+w8[2]*yr[2]+w8[3]*yr[3]
                +w8[4]*yr[4]+w8[5]*yr[5]+w8[6]*yr[6]+w8[7]*yr[7];
      }
    }
#pragma unroll
    for(int r=0;r<32;r++) qs[(size_t)(r0+r)*256+t]=acc2[r];
  }
}

extern "C" void kernel_launch(void* const* d_in, const int* in_sizes, int n_in,
                              void* d_out, int out_size, void* d_ws, size_t ws_size,
                              hipStream_t stream){
  const float* inputs=(const float*)d_in[0];
  const float* sinit =(const float*)d_in[1];
  const float* Wq =(const float*)d_in[2];
  const float* Wk =(const float*)d_in[3];
  const float* Wv =(const float*)d_in[4];
  const float* Wih=(const float*)d_in[5];
  const float* Whh=(const float*)d_in[6];
  const float* bih=(const float*)d_in[7];
  const float* bhh=(const float*)d_in[8];
  const float* lin_g=(const float*)d_in[9];
  const float* lin_b=(const float*)d_in[10];
  const float* ls_g=(const float*)d_in[11];
  const float* ls_b=(const float*)d_in[12];
  const float* lm_g=(const float*)d_in[13];
  const float* lm_b=(const float*)d_in[14];
  const float* W1=(const float*)d_in[15];
  const float* b1=(const float*)d_in[16];
  const float* W2=(const float*)d_in[17];
  const float* b2=(const float*)d_in[18];

  char* w=(char*)d_ws;
  __half* x    =(__half*)w; w += (size_t)BB*NN*DD*2;        // 134.2 MB
  float* qs    =(float*)w;  w += 512*256*4;
  float* slots =(float*)w;  w += 512*256*4;
  __half* slotsh=(__half*)w; w += 512*256*2;
  __half* M2h  =(__half*)w; w += 256*256*2;
  __half* Wg   =(__half*)w; w += 256*1536*2;
  __half* W1t  =(__half*)w; w += 256*1024*2;
  __half* W2t  =(__half*)w; w += 1024*256*2;
  float* hb    =(float*)w;  w += 512*256*4;
  __half* z1h  =(__half*)w; w += (size_t)512*1024*2;
  float* gl_   =(float*)w;  w += (size_t)512*1536*4;        // 3.1 MB
  float* aggZ  =(float*)w;  w += (size_t)788160*4;

  // zero-region layout: aggF x3 | wsumF x3 | o2 x3 | cnt x3
  float* aggFv[3]; float* wsumFv[3]; float* o2v[3]; int* cntv[3];
  for(int i=0;i<3;i++){
    aggFv[i]  = aggZ + (size_t)i*131072;
    wsumFv[i] = aggZ + 393216 + (size_t)i*512;
    o2v[i]    = aggZ + 394752 + (size_t)i*131072;
    cntv[i]   = (int*)(aggZ + 787968 + (size_t)i*64);
  }

  hipLaunchKernelGGL(kp_all, dim3(5767), dim3(256), 0, stream,
                     Whh, W1, W2, sinit, Wih, Wv, Wq, Wk,
                     Wg, W1t, W2t, slots, M2h, aggZ);
  hipLaunchKernelGGL(k_ln_x, dim3(65536),dim3(256), 0, stream, inputs, lin_g, lin_b, x);
  hipLaunchKernelGGL(k_pre,  dim3(512),  dim3(256), 0, stream, slots, ls_g, ls_b, M2h, qs, slotsh);
  for(int it=0; it<NITER; ++it){
    int last = (it==NITER-1);
    float* dst = last ? (float*)d_out : slots;
    hipLaunchKernelGGL(k_att,   dim3(1024), dim3(256), 0, stream, x, qs, aggFv[it], wsumFv[it]);
    hipLaunchKernelGGL(t_gates, dim3(384),  dim3(256), 0, stream, aggFv[it], wsumFv[it], slotsh, Wg, bih, bhh, gl_);
    hipLaunchKernelGGL(t_mlp1g, dim3(256),  dim3(256), 0, stream, gl_, slots, lm_g, lm_b, W1t, b1, hb, z1h);
    hipLaunchKernelGGL(t_mlp2f, dim3(512),  dim3(256), 0, stream, z1h, W2t, hb, b2, ls_g, ls_b, M2h,
                       o2v[it], cntv[it], dst, slotsh, qs, last);
  }
}

// Round 15
// 417.974 us; speedup vs baseline: 2.0004x; 1.3940x over previous
//
#include <hip/hip_runtime.h>
#include <hip/hip_fp16.h>
#include <hip/hip_bf16.h>

// SlotAttention restructured:
//  dots = qs . x   with qs = LN(slots) @ (scale * Wq^T Wk)   (K never materialized)
//  updates folded:  gates_ih = (agg*fac) @ (Wih@Wv)^T        (V and upd never materialized)
// x = LN(inputs) fp16. fp32 accumulation. Output fp32.
// Measured structural facts: grid.sync ~35us (R13), 128-blk chunk machine
// starves TLP (R12), atomic+last-block fusion loses (R14). R15 = R11 base
// (best, 403us) + ONLY the safe R14 piece: t_gruln folded into t_mlp1g.
// 21 -> 18 dispatches.

#define BB 64
#define NN 4096
#define DD 256
#define NSL 8
#define NITER 3

__device__ __forceinline__ float wredsum(float v){
#pragma unroll
  for(int m=32;m;m>>=1) v += __shfl_xor(v, m, 64);
  return v;
}
__device__ __forceinline__ float2 u2f2(unsigned u){ __half2 h; __builtin_memcpy(&h,&u,4); return __half22float2(h); }
__device__ __forceinline__ float sigm(float v){ return 1.0f/(1.0f+__expf(-v)); }

union U4 { uint4 u; __half2 h[4]; };

__device__ __forceinline__ void st8(float* dst, uint4 uu){
  U4 v; v.u=uu;
  float2 f0=__half22float2(v.h[0]), f1=__half22float2(v.h[1]),
         f2=__half22float2(v.h[2]), f3=__half22float2(v.h[3]);
  dst[0]=f0.x; dst[1]=f0.y; dst[2]=f1.x; dst[3]=f1.y;
  dst[4]=f2.x; dst[5]=f2.y; dst[6]=f3.x; dst[7]=f3.y;
}

#define F8(a,b,nm) float nm[8]={a.x,a.y,a.z,a.w,b.x,b.y,b.z,b.w}

// ---------------- merged prep: weights + slots + WC GEMM + M GEMM + agg zero ----------------
__global__ __launch_bounds__(256) void kp_all(
    const float* __restrict__ Whh, const float* __restrict__ W1,
    const float* __restrict__ W2,  const float* __restrict__ sinit,
    const float* __restrict__ Wih, const float* __restrict__ Wv,
    const float* __restrict__ Wq,  const float* __restrict__ Wk,
    __half* __restrict__ Wg, __half* __restrict__ W1t, __half* __restrict__ W2t,
    float* __restrict__ slots, __half* __restrict__ M2h, float* __restrict__ zbuf){
  int bid=blockIdx.x, t=threadIdx.x;
  if(bid<1664){
    for(int idx=bid*256+t; idx<851968; idx+=1664*256){
      if(idx<196608){ int col=idx>>8, c=idx&255; Wg[(size_t)c*1536+768+col]=__float2half(Whh[idx]); }
      else if(idx<458752){ int k=idx-196608; int col=k>>8, c=k&255; W1t[(size_t)c*1024+col]=__float2half(W1[k]); }
      else if(idx<720896){ int k=idx-458752; int col=k>>10, c=k&1023; W2t[(size_t)c*256+col]=__float2half(W2[k]); }
      else { int k=idx-720896; slots[k]=sinit[k&2047]; }
    }
  } else if(bid<2432){
    int col=bid-1664;            // 0..767
    __shared__ float wr[256];
    wr[t]=Wih[col*256+t];
    __syncthreads();
    float acc=0.f;
#pragma unroll 8
    for(int d=0;d<256;d++) acc += wr[d]*Wv[d*256+t];
    Wg[(size_t)t*1536+col]=__float2half(acc);
  } else if(bid<2688){
    int c=bid-2432;              // 0..255
    float acc=0.f;
#pragma unroll 8
    for(int d=0;d<256;d++) acc += Wq[d*256+t]*Wk[d*256+c];
    M2h[(size_t)c*256+t]=__float2half(acc*0.0625f);
  } else {
    int idx=(bid-2688)*256+t;
    if(idx<394752) zbuf[idx]=0.f;
  }
}

// ---------------- x = LN(inputs) -> fp16 ----------------
__global__ __launch_bounds__(256) void k_ln_x(const float* __restrict__ in, const float* __restrict__ g,
                                              const float* __restrict__ bbv, __half* __restrict__ x){
  int row  = blockIdx.x*4 + (threadIdx.x>>6);
  int lane = threadIdx.x&63;
  const float4 v = ((const float4*)(in + (size_t)row*DD))[lane];
  float s  = v.x+v.y+v.z+v.w;
  float ss = v.x*v.x+v.y*v.y+v.z*v.z+v.w*v.w;
  s = wredsum(s); ss = wredsum(ss);
  float m = s*(1.0f/256.0f);
  float r = rsqrtf(ss*(1.0f/256.0f) - m*m + 1e-5f);
  float4 gv = ((const float4*)g)[lane];
  float4 bv = ((const float4*)bbv)[lane];
  float y0=(v.x-m)*r*gv.x+bv.x, y1=(v.y-m)*r*gv.y+bv.y;
  float y2=(v.z-m)*r*gv.z+bv.z, y3=(v.w-m)*r*gv.w+bv.w;
  __half2 h0=__floats2half2_rn(y0,y1), h1=__floats2half2_rn(y2,y3);
  uint2 u; __builtin_memcpy(&u.x,&h0,4); __builtin_memcpy(&u.y,&h1,4);
  ((uint2*)(x + (size_t)row*DD))[lane] = u;
}

// ---------------- initial qs = LN(slots) @ M (once); also writes slotsh ----------------
__global__ __launch_bounds__(256) void k_pre(const float* __restrict__ slots, const float* __restrict__ g,
                                             const float* __restrict__ bbv, const __half* __restrict__ M2h,
                                             float* __restrict__ qs, __half* __restrict__ slotsh){
  int row = blockIdx.x;      // 0..511
  int t = threadIdx.x;
  __shared__ __align__(16) float sn[256];
  __shared__ float red[8];
  float v = slots[row*256 + t];
  slotsh[(size_t)row*256+t]=__float2half(v);
  float s = wredsum(v), ss = wredsum(v*v);
  int wid=t>>6, lane=t&63;
  if(lane==0){ red[wid]=s; red[4+wid]=ss; }
  __syncthreads();
  float S  = red[0]+red[1]+red[2]+red[3];
  float SS = red[4]+red[5]+red[6]+red[7];
  float m = S*(1.0f/256.0f);
  float r = rsqrtf(SS*(1.0f/256.0f) - m*m + 1e-5f);
  sn[t] = (v-m)*r*g[t]+bbv[t];
  __syncthreads();
  const uint4* w4 = (const uint4*)(M2h + (size_t)t*256);
  float acc=0.f;
#pragma unroll 4
  for(int kk=0;kk<32;kk++){
    U4 w; w.u=w4[kk];
#pragma unroll
    for(int q=0;q<4;q++){
      float2 f=__half22float2(w.h[q]);
      acc += sn[kk*8+2*q]*f.x + sn[kk*8+2*q+1]*f.y;
    }
  }
  qs[row*256+t]=acc;
}

// ---------------- fused attention: dots+softmax -> w -> partial agg (atomic) ----------------
__global__ __launch_bounds__(256) void k_att(const __half* __restrict__ x, const float* __restrict__ qs,
                                             float* __restrict__ aggF, float* __restrict__ wsumF){
  int b = blockIdx.x>>4;
  int t = threadIdx.x;
  size_t j = (size_t)blockIdx.x*256 + t;
  __shared__ __align__(16) float qt[256][8];
  __shared__ __align__(16) float wl[256][8];
  __shared__ __align__(16) float aggl[4][2048];
  __shared__ float wsl[4][8];
  const float* qb = qs + b*2048;
  for(int e=t;e<2048;e+=256) qt[e&255][e>>8]=qb[e];
  __syncthreads();
  const uint4* xr = (const uint4*)(x + j*DD);
  float pd[8]={0,0,0,0,0,0,0,0};
#pragma unroll 2
  for(int ch=0; ch<32; ch++){
    uint4 u = xr[ch];
    float2 f0=u2f2(u.x), f1=u2f2(u.y), f2=u2f2(u.z), f3=u2f2(u.w);
    float xv[8]={f0.x,f0.y,f1.x,f1.y,f2.x,f2.y,f3.x,f3.y};
    int c0=ch*8;
#pragma unroll
    for(int cc=0;cc<8;cc++){
      const float4* qp=(const float4*)&qt[c0+cc][0];
      float4 qa=qp[0], qc=qp[1];
      float xvv=xv[cc];
      pd[0]+=qa.x*xvv; pd[1]+=qa.y*xvv; pd[2]+=qa.z*xvv; pd[3]+=qa.w*xvv;
      pd[4]+=qc.x*xvv; pd[5]+=qc.y*xvv; pd[6]+=qc.z*xvv; pd[7]+=qc.w*xvv;
    }
  }
  float mx=pd[0];
#pragma unroll
  for(int i=1;i<8;i++) mx=fmaxf(mx,pd[i]);
  float ev[8]; float ssum=0.f;
#pragma unroll
  for(int i=0;i<8;i++){ ev[i]=__expf(pd[i]-mx); ssum+=ev[i]; }
  float inv=1.0f/ssum;
#pragma unroll
  for(int i=0;i<8;i++) wl[t][i]=ev[i]*inv+1e-5f;
  __syncthreads();
  int wid=t>>6, lane=t&63;
  float acc[8][4];
#pragma unroll
  for(int i=0;i<8;i++){ acc[i][0]=0;acc[i][1]=0;acc[i][2]=0;acc[i][3]=0; }
  float ws[8]={0,0,0,0,0,0,0,0};
  for(int r=0;r<64;r++){
    int jl = wid*64 + r;
    uint2 u = ((const uint2*)(x + ((size_t)blockIdx.x*256 + jl)*DD))[lane];
    float2 f01=u2f2(u.x), f23=u2f2(u.y);
    const float4* wp=(const float4*)&wl[jl][0];
    float4 wa=wp[0], wb_=wp[1];
    float wv[8]={wa.x,wa.y,wa.z,wa.w,wb_.x,wb_.y,wb_.z,wb_.w};
    float xv[4]={f01.x,f01.y,f23.x,f23.y};
#pragma unroll
    for(int i=0;i<8;i++){
      acc[i][0]+=wv[i]*xv[0]; acc[i][1]+=wv[i]*xv[1];
      acc[i][2]+=wv[i]*xv[2]; acc[i][3]+=wv[i]*xv[3];
      ws[i]+=wv[i];
    }
  }
#pragma unroll
  for(int i=0;i<8;i++){
    float4 st={acc[i][0],acc[i][1],acc[i][2],acc[i][3]};
    *((float4*)&aggl[wid][i*256 + lane*4])=st;
  }
  if(lane==0){
#pragma unroll
    for(int i=0;i<8;i++) wsl[wid][i]=ws[i];
  }
  __syncthreads();
  float* ab = aggF + (size_t)b*2048;
  for(int e=t;e<2048;e+=256)
    atomicAdd(&ab[e], aggl[0][e]+aggl[1][e]+aggl[2][e]+aggl[3][e]);
  if(t<8) atomicAdd(&wsumF[b*8+t], wsl[0][t]+wsl[1][t]+wsl[2][t]+wsl[3][t]);
}

// ---------------- t_gates: gl[512][1536] = [(agg*fac)@WC^T+bih | slotsh@Whh^T+bhh] ----------------
__global__ __launch_bounds__(256) void t_gates(const float* __restrict__ aggF,
    const float* __restrict__ wsumF,
    const __half* __restrict__ slotsh, const __half* __restrict__ Wg,
    const float* __restrict__ bih, const float* __restrict__ bhh,
    float* __restrict__ gl){
  int rt=blockIdx.x&15, ct=blockIdx.x>>4;
  int t=threadIdx.x;
  int r0=rt*32, c0=ct*64;
  __shared__ __align__(16) float Af[32][264];
  __shared__ __align__(16) float Wf[64][68];
  __shared__ float facS[32];
  if(ct<12){
    if(t<32) facS[t]=4096.0f/wsumF[r0+t];
    __syncthreads();
#pragma unroll
    for(int q=0;q<8;q++){
      int u=q*256+t;
      int row=u>>6, c4=u&63;
      float4 v=((const float4*)(aggF+(size_t)(r0+row)*256))[c4];
      float f=facS[row];
      v.x*=f; v.y*=f; v.z*=f; v.w*=f;
      *(float4*)&Af[row][c4*4]=v;
    }
  } else {
#pragma unroll
    for(int q=0;q<4;q++){
      int u=q*256+t;
      int row=u>>5, kk=u&31;
      st8(&Af[row][kk*8], ((const uint4*)(slotsh + ((size_t)(r0+row))*256))[kk]);
    }
  }
  float acc[2][4]={{0,0,0,0},{0,0,0,0}};
  int tx=t&15, ty=t>>4;
  for(int kc=0;kc<4;kc++){
    __syncthreads();
#pragma unroll
    for(int q=0;q<2;q++){
      int u=q*256+t;
      int kk=u>>3, cb=u&7;
      st8(&Wf[kk][cb*8], ((const uint4*)(Wg + (size_t)(kc*64+kk)*1536 + c0))[cb]);
    }
    __syncthreads();
#pragma unroll
    for(int k4=0;k4<16;k4++){
      float4 a0=*(const float4*)&Af[ty][kc*64+k4*4];
      float4 a1=*(const float4*)&Af[ty+16][kc*64+k4*4];
      float av0[4]={a0.x,a0.y,a0.z,a0.w};
      float av1[4]={a1.x,a1.y,a1.z,a1.w};
#pragma unroll
      for(int jj=0;jj<4;jj++){
        float4 wv=*(const float4*)&Wf[k4*4+jj][tx*4];
        acc[0][0]+=av0[jj]*wv.x; acc[0][1]+=av0[jj]*wv.y; acc[0][2]+=av0[jj]*wv.z; acc[0][3]+=av0[jj]*wv.w;
        acc[1][0]+=av1[jj]*wv.x; acc[1][1]+=av1[jj]*wv.y; acc[1][2]+=av1[jj]*wv.z; acc[1][3]+=av1[jj]*wv.w;
      }
    }
  }
  int col=c0+tx*4;
  const float* bb=(ct<12)? bih : bhh;
  int bcol=(ct<12)? col : col-768;
  float4 bv=*(const float4*)&bb[bcol];
  float4 o0={acc[0][0]+bv.x, acc[0][1]+bv.y, acc[0][2]+bv.z, acc[0][3]+bv.w};
  float4 o1={acc[1][0]+bv.x, acc[1][1]+bv.y, acc[1][2]+bv.z, acc[1][3]+bv.w};
  *(float4*)&gl[(size_t)(r0+ty)*1536+col]=o0;
  *(float4*)&gl[(size_t)(r0+ty+16)*1536+col]=o1;
}

// ---------------- t_mlp1g: GRU+LN (recomputed per block) + mlp1 GEMM -> z1h ----------------
// grid 256 = 16 rt x 16 ct, 256 thr
__global__ __launch_bounds__(256) void t_mlp1g(const float* __restrict__ gl,
    const float* __restrict__ slots,
    const float* __restrict__ lm_g, const float* __restrict__ lm_b,
    const __half* __restrict__ W1t, const float* __restrict__ b1,
    float* __restrict__ hb, __half* __restrict__ z1h){
  int rt=blockIdx.x&15, ct=blockIdx.x>>4;
  int t=threadIdx.x;
  int r0=rt*32, c0=ct*64;
  __shared__ __align__(16) float Af[32][264];
  __shared__ __align__(16) float Wf[64][68];
  int lane32=t&31, rowg=t>>5;
#pragma unroll
  for(int p=0;p<4;p++){
    int row=p*8+rowg, gr=r0+row, c8=lane32*8;
    const float* g=gl+(size_t)gr*1536;
    float4 A0=*(const float4*)&g[c8],      A1=*(const float4*)&g[c8+4];      F8(A0,A1,gi);
    float4 B0=*(const float4*)&g[256+c8],  B1=*(const float4*)&g[256+c8+4];  F8(B0,B1,gz);
    float4 C0=*(const float4*)&g[512+c8],  C1=*(const float4*)&g[512+c8+4];  F8(C0,C1,gn);
    float4 D0=*(const float4*)&g[768+c8],  D1=*(const float4*)&g[768+c8+4];  F8(D0,D1,hr);
    float4 E0=*(const float4*)&g[1024+c8], E1=*(const float4*)&g[1024+c8+4]; F8(E0,E1,hz);
    float4 G0=*(const float4*)&g[1280+c8], G1=*(const float4*)&g[1280+c8+4]; F8(G0,G1,hn);
    float4 H0=*(const float4*)&slots[(size_t)gr*256+c8];
    float4 H1=*(const float4*)&slots[(size_t)gr*256+c8+4]; F8(H0,H1,hp);
    float hv8[8]; float s=0.f,qq=0.f;
#pragma unroll
    for(int k=0;k<8;k++){
      float rr=sigm(gi[k]+hr[k]), zz=sigm(gz[k]+hz[k]);
      float nn=tanhf(gn[k]+rr*hn[k]);
      float hv=(1.0f-zz)*nn+zz*hp[k];
      hv8[k]=hv; s+=hv; qq+=hv*hv;
    }
#pragma unroll
    for(int m=16;m;m>>=1){ s+=__shfl_xor(s,m,64); qq+=__shfl_xor(qq,m,64); }
    float mean=s*(1.0f/256.0f);
    float rs=rsqrtf(qq*(1.0f/256.0f)-mean*mean+1e-5f);
    float4 L0=*(const float4*)&lm_g[c8], L1=*(const float4*)&lm_g[c8+4]; F8(L0,L1,lg);
    float4 M0=*(const float4*)&lm_b[c8], M1=*(const float4*)&lm_b[c8+4]; F8(M0,M1,lb);
#pragma unroll
    for(int k=0;k<8;k++) Af[row][c8+k]=(hv8[k]-mean)*rs*lg[k]+lb[k];
    if(ct==0){
      float4 o0={hv8[0],hv8[1],hv8[2],hv8[3]}, o1={hv8[4],hv8[5],hv8[6],hv8[7]};
      *(float4*)&hb[(size_t)gr*256+c8]=o0;
      *(float4*)&hb[(size_t)gr*256+c8+4]=o1;
    }
  }
  float acc[2][4]={{0,0,0,0},{0,0,0,0}};
  int tx=t&15, ty=t>>4;
  for(int kc=0;kc<4;kc++){
    __syncthreads();
#pragma unroll
    for(int q=0;q<2;q++){
      int u=q*256+t; int kk=u>>3, cb=u&7;
      st8(&Wf[kk][cb*8], ((const uint4*)(W1t + (size_t)(kc*64+kk)*1024 + c0))[cb]);
    }
    __syncthreads();
#pragma unroll
    for(int k4=0;k4<16;k4++){
      float4 a0=*(const float4*)&Af[ty][kc*64+k4*4];
      float4 a1=*(const float4*)&Af[ty+16][kc*64+k4*4];
      float av0[4]={a0.x,a0.y,a0.z,a0.w};
      float av1[4]={a1.x,a1.y,a1.z,a1.w};
#pragma unroll
      for(int jj=0;jj<4;jj++){
        float4 wv=*(const float4*)&Wf[k4*4+jj][tx*4];
        acc[0][0]+=av0[jj]*wv.x; acc[0][1]+=av0[jj]*wv.y; acc[0][2]+=av0[jj]*wv.z; acc[0][3]+=av0[jj]*wv.w;
        acc[1][0]+=av1[jj]*wv.x; acc[1][1]+=av1[jj]*wv.y; acc[1][2]+=av1[jj]*wv.z; acc[1][3]+=av1[jj]*wv.w;
      }
    }
  }
  int col=c0+tx*4;
  float4 bv=*(const float4*)&b1[col];
#pragma unroll
  for(int rr2=0;rr2<2;rr2++){
    float v0=acc[rr2][0]+bv.x, v1=acc[rr2][1]+bv.y, v2=acc[rr2][2]+bv.z, v3=acc[rr2][3]+bv.w;
    v0=v0>0.f?v0:0.01f*v0; v1=v1>0.f?v1:0.01f*v1;
    v2=v2>0.f?v2:0.01f*v2; v3=v3>0.f?v3:0.01f*v3;
    __half2 p0=__floats2half2_rn(v0,v1), p1=__floats2half2_rn(v2,v3);
    uint2 u2; __builtin_memcpy(&u2.x,&p0,4); __builtin_memcpy(&u2.y,&p1,4);
    *(uint2*)&z1h[(size_t)(r0+ty+rr2*16)*1024+col]=u2;
  }
}

// ---------------- t_mlp2p: partial z1h@W2^T, K=1024 split 8x128 ----------------
__global__ __launch_bounds__(256) void t_mlp2p(const __half* __restrict__ z1h,
    const __half* __restrict__ W2t, float* __restrict__ pp){
  int b=blockIdx.x;
  int rt=b&15, ct=(b>>4)&3, kc=b>>6;
  int t=threadIdx.x;
  int r0=rt*32, c0=ct*64;
  __shared__ __align__(16) float Af[32][136];
  __shared__ __align__(16) float Wf[128][68];
#pragma unroll
  for(int q=0;q<2;q++){
    int u=q*256+t;
    int row=u>>4, seg=u&15;
    st8(&Af[row][seg*8], ((const uint4*)(z1h + (size_t)(r0+row)*1024 + kc*128))[seg]);
  }
#pragma unroll
  for(int q=0;q<4;q++){
    int u=q*256+t;
    int kk=u>>3, cb=u&7;
    st8(&Wf[kk][cb*8], ((const uint4*)(W2t + (size_t)(kc*128+kk)*256 + c0))[cb]);
  }
  __syncthreads();
  float acc[2][4]={{0,0,0,0},{0,0,0,0}};
  int tx=t&15, ty=t>>4;
#pragma unroll
  for(int k4=0;k4<32;k4++){
    float4 a0=*(const float4*)&Af[ty][k4*4];
    float4 a1=*(const float4*)&Af[ty+16][k4*4];
    float av0[4]={a0.x,a0.y,a0.z,a0.w};
    float av1[4]={a1.x,a1.y,a1.z,a1.w};
#pragma unroll
    for(int jj=0;jj<4;jj++){
      float4 wv=*(const float4*)&Wf[k4*4+jj][tx*4];
      acc[0][0]+=av0[jj]*wv.x; acc[0][1]+=av0[jj]*wv.y; acc[0][2]+=av0[jj]*wv.z; acc[0][3]+=av0[jj]*wv.w;
      acc[1][0]+=av1[jj]*wv.x; acc[1][1]+=av1[jj]*wv.y; acc[1][2]+=av1[jj]*wv.z; acc[1][3]+=av1[jj]*wv.w;
    }
  }
  int col=c0+tx*4;
  float4 o0={acc[0][0],acc[0][1],acc[0][2],acc[0][3]};
  float4 o1={acc[1][0],acc[1][1],acc[1][2],acc[1][3]};
  *(float4*)&pp[((size_t)kc*512 + r0+ty)*256+col]=o0;
  *(float4*)&pp[((size_t)kc*512 + r0+ty+16)*256+col]=o1;
}

// ---------------- t_fin: reduce partials + residual; slot-LN + qs (non-last) ----------------
__global__ __launch_bounds__(512) void t_fin(const float* __restrict__ hb, const float* __restrict__ pp,
    const float* __restrict__ b2, const float* __restrict__ ls_g, const float* __restrict__ ls_b,
    const __half* __restrict__ M2h, float* __restrict__ dst,
    __half* __restrict__ slotsh, float* __restrict__ qs, int last){
  int t=threadIdx.x;
  int r=t>>8, c=t&255; int row=blockIdx.x*2+r;
  __shared__ float ysl[2][256];
  __shared__ float redS[2][4], redQ[2][4];
  float s = hb[(size_t)row*256+c] + b2[c];
#pragma unroll
  for(int kc=0;kc<8;kc++) s += pp[((size_t)kc*512+row)*256+c];
  dst[(size_t)row*256+c]=s;
  if(last) return;
  slotsh[(size_t)row*256+c]=__float2half(s);
  float su=wredsum(s), sq=wredsum(s*s);
  if((t&63)==0){ redS[r][(t>>6)&3]=su; redQ[r][(t>>6)&3]=sq; }
  __syncthreads();
  float S=redS[r][0]+redS[r][1]+redS[r][2]+redS[r][3];
  float SS=redQ[r][0]+redQ[r][1]+redQ[r][2]+redQ[r][3];
  float m=S*(1.0f/256.0f);
  float rs=rsqrtf(SS*(1.0f/256.0f)-m*m+1e-5f);
  ysl[r][c]=(s-m)*rs*ls_g[c]+ls_b[c];
  __syncthreads();
  const uint4* m4=(const uint4*)(M2h+(size_t)c*256);
  float acc=0.f;
#pragma unroll 4
  for(int kk=0;kk<32;kk++){
    U4 w; w.u=m4[kk];
#pragma unroll
    for(int q=0;q<4;q++){
      float2 f=__half22float2(w.h[q]);
      acc += ysl[r][kk*8+2*q]*f.x + ysl[r][kk*8+2*q+1]*f.y;
    }
  }
  qs[(size_t)row*256+c]=acc;
}

extern "C" void kernel_launch(void* const* d_in, const int* in_sizes, int n_in,
                              void* d_out, int out_size, void* d_ws, size_t ws_size,
                              hipStream_t stream){
  const float* inputs=(const float*)d_in[0];
  const float* sinit =(const float*)d_in[1];
  const float* Wq =(const float*)d_in[2];
  const float* Wk =(const float*)d_in[3];
  const float* Wv =(const float*)d_in[4];
  const float* Wih=(const float*)d_in[5];
  const float* Whh=(const float*)d_in[6];
  const float* bih=(const float*)d_in[7];
  const float* bhh=(const float*)d_in[8];
  const float* lin_g=(const float*)d_in[9];
  const float* lin_b=(const float*)d_in[10];
  const float* ls_g=(const float*)d_in[11];
  const float* ls_b=(const float*)d_in[12];
  const float* lm_g=(const float*)d_in[13];
  const float* lm_b=(const float*)d_in[14];
  const float* W1=(const float*)d_in[15];
  const float* b1=(const float*)d_in[16];
  const float* W2=(const float*)d_in[17];
  const float* b2=(const float*)d_in[18];

  char* w=(char*)d_ws;
  __half* x    =(__half*)w; w += (size_t)BB*NN*DD*2;        // 134.2 MB
  float* qs    =(float*)w;  w += 512*256*4;
  float* slots =(float*)w;  w += 512*256*4;
  __half* slotsh=(__half*)w; w += 512*256*2;
  __half* M2h  =(__half*)w; w += 256*256*2;
  __half* Wg   =(__half*)w; w += 256*1536*2;
  __half* W1t  =(__half*)w; w += 256*1024*2;
  __half* W2t  =(__half*)w; w += 1024*256*2;
  float* hb    =(float*)w;  w += 512*256*4;
  __half* z1h  =(__half*)w; w += (size_t)512*1024*2;
  float* pp    =(float*)w;  w += (size_t)8*512*256*4;       // 4.2 MB
  float* gl_   =(float*)w;  w += (size_t)512*1536*4;        // 3.1 MB
  float* aggZ  =(float*)w;  w += (size_t)(3*512*256 + 3*512)*4;

  float* aggFv[3]; float* wsumFv[3];
  for(int i=0;i<3;i++){ aggFv[i]=aggZ + (size_t)i*131072; wsumFv[i]=aggZ + 393216 + (size_t)i*512; }

  hipLaunchKernelGGL(kp_all, dim3(4230), dim3(256), 0, stream,
                     Whh, W1, W2, sinit, Wih, Wv, Wq, Wk,
                     Wg, W1t, W2t, slots, M2h, aggZ);
  hipLaunchKernelGGL(k_ln_x, dim3(65536),dim3(256), 0, stream, inputs, lin_g, lin_b, x);
  hipLaunchKernelGGL(k_pre,  dim3(512),  dim3(256), 0, stream, slots, ls_g, ls_b, M2h, qs, slotsh);
  for(int it=0; it<NITER; ++it){
    int last = (it==NITER-1);
    float* dst = last ? (float*)d_out : slots;
    hipLaunchKernelGGL(k_att,   dim3(1024), dim3(256), 0, stream, x, qs, aggFv[it], wsumFv[it]);
    hipLaunchKernelGGL(t_gates, dim3(384),  dim3(256), 0, stream, aggFv[it], wsumFv[it], slotsh, Wg, bih, bhh, gl_);
    hipLaunchKernelGGL(t_mlp1g, dim3(256),  dim3(256), 0, stream, gl_, slots, lm_g, lm_b, W1t, b1, hb, z1h);
    hipLaunchKernelGGL(t_mlp2p, dim3(512),  dim3(256), 0, stream, z1h, W2t, pp);
    hipLaunchKernelGGL(t_fin,   dim3(256),  dim3(512), 0, stream, hb, pp, b2, ls_g, ls_b, M2h,
                       dst, slotsh, qs, last);
  }
}

// Round 16
// 391.015 us; speedup vs baseline: 2.1383x; 1.0689x over previous
//
#include <hip/hip_runtime.h>
#include <hip/hip_fp16.h>
#include <hip/hip_bf16.h>

// SlotAttention restructured:
//  dots = qs . x   with qs = LN(slots) @ (scale * Wq^T Wk)   (K never materialized)
//  updates folded:  gates_ih = (agg*fac) @ (Wih@Wv)^T        (V and upd never materialized)
// x = LN(inputs) fp16. fp32 accumulation. Output fp32.
// Structural facts (measured): cross-block sync ~35us (R13), kernel boundary
// ~6us, chunk-machine starves TLP (R12), atomic+last-block fusion loses (R14),
// redundant GRU recompute loses (R15). R11's 5-phase tail is phase-minimal.
// R16 = R11 + micro-opts: k_att unroll-4 both loops, ln_x grid-stride 8192.

#define BB 64
#define NN 4096
#define DD 256
#define NSL 8
#define NITER 3

__device__ __forceinline__ float wredsum(float v){
#pragma unroll
  for(int m=32;m;m>>=1) v += __shfl_xor(v, m, 64);
  return v;
}
__device__ __forceinline__ float2 u2f2(unsigned u){ __half2 h; __builtin_memcpy(&h,&u,4); return __half22float2(h); }
__device__ __forceinline__ float sigm(float v){ return 1.0f/(1.0f+__expf(-v)); }

union U4 { uint4 u; __half2 h[4]; };

__device__ __forceinline__ void st8(float* dst, uint4 uu){
  U4 v; v.u=uu;
  float2 f0=__half22float2(v.h[0]), f1=__half22float2(v.h[1]),
         f2=__half22float2(v.h[2]), f3=__half22float2(v.h[3]);
  dst[0]=f0.x; dst[1]=f0.y; dst[2]=f1.x; dst[3]=f1.y;
  dst[4]=f2.x; dst[5]=f2.y; dst[6]=f3.x; dst[7]=f3.y;
}

// ---------------- merged prep: weights + slots + WC GEMM + M GEMM + agg zero ----------------
__global__ __launch_bounds__(256) void kp_all(
    const float* __restrict__ Whh, const float* __restrict__ W1,
    const float* __restrict__ W2,  const float* __restrict__ sinit,
    const float* __restrict__ Wih, const float* __restrict__ Wv,
    const float* __restrict__ Wq,  const float* __restrict__ Wk,
    __half* __restrict__ Wg, __half* __restrict__ W1t, __half* __restrict__ W2t,
    float* __restrict__ slots, __half* __restrict__ M2h, float* __restrict__ zbuf){
  int bid=blockIdx.x, t=threadIdx.x;
  if(bid<1664){
    for(int idx=bid*256+t; idx<851968; idx+=1664*256){
      if(idx<196608){ int col=idx>>8, c=idx&255; Wg[(size_t)c*1536+768+col]=__float2half(Whh[idx]); }
      else if(idx<458752){ int k=idx-196608; int col=k>>8, c=k&255; W1t[(size_t)c*1024+col]=__float2half(W1[k]); }
      else if(idx<720896){ int k=idx-458752; int col=k>>10, c=k&1023; W2t[(size_t)c*256+col]=__float2half(W2[k]); }
      else { int k=idx-720896; slots[k]=sinit[k&2047]; }
    }
  } else if(bid<2432){
    int col=bid-1664;            // 0..767
    __shared__ float wr[256];
    wr[t]=Wih[col*256+t];
    __syncthreads();
    float acc=0.f;
#pragma unroll 8
    for(int d=0;d<256;d++) acc += wr[d]*Wv[d*256+t];
    Wg[(size_t)t*1536+col]=__float2half(acc);
  } else if(bid<2688){
    int c=bid-2432;              // 0..255
    float acc=0.f;
#pragma unroll 8
    for(int d=0;d<256;d++) acc += Wq[d*256+t]*Wk[d*256+c];
    M2h[(size_t)c*256+t]=__float2half(acc*0.0625f);
  } else {
    int idx=(bid-2688)*256+t;
    if(idx<394752) zbuf[idx]=0.f;
  }
}

// ---------------- x = LN(inputs) -> fp16 (grid-stride, 8192 blocks) ----------------
__global__ __launch_bounds__(256) void k_ln_x(const float* __restrict__ in, const float* __restrict__ g,
                                              const float* __restrict__ bbv, __half* __restrict__ x){
  int lane = threadIdx.x&63;
  float4 gv = ((const float4*)g)[lane];
  float4 bv = ((const float4*)bbv)[lane];
  for(int row = blockIdx.x*4 + (threadIdx.x>>6); row < BB*NN; row += gridDim.x*4){
    const float4 v = ((const float4*)(in + (size_t)row*DD))[lane];
    float s  = v.x+v.y+v.z+v.w;
    float ss = v.x*v.x+v.y*v.y+v.z*v.z+v.w*v.w;
    s = wredsum(s); ss = wredsum(ss);
    float m = s*(1.0f/256.0f);
    float r = rsqrtf(ss*(1.0f/256.0f) - m*m + 1e-5f);
    float y0=(v.x-m)*r*gv.x+bv.x, y1=(v.y-m)*r*gv.y+bv.y;
    float y2=(v.z-m)*r*gv.z+bv.z, y3=(v.w-m)*r*gv.w+bv.w;
    __half2 h0=__floats2half2_rn(y0,y1), h1=__floats2half2_rn(y2,y3);
    uint2 u; __builtin_memcpy(&u.x,&h0,4); __builtin_memcpy(&u.y,&h1,4);
    ((uint2*)(x + (size_t)row*DD))[lane] = u;
  }
}

// ---------------- initial qs = LN(slots) @ M (once); also writes slotsh ----------------
__global__ __launch_bounds__(256) void k_pre(const float* __restrict__ slots, const float* __restrict__ g,
                                             const float* __restrict__ bbv, const __half* __restrict__ M2h,
                                             float* __restrict__ qs, __half* __restrict__ slotsh){
  int row = blockIdx.x;      // 0..511
  int t = threadIdx.x;
  __shared__ __align__(16) float sn[256];
  __shared__ float red[8];
  float v = slots[row*256 + t];
  slotsh[(size_t)row*256+t]=__float2half(v);
  float s = wredsum(v), ss = wredsum(v*v);
  int wid=t>>6, lane=t&63;
  if(lane==0){ red[wid]=s; red[4+wid]=ss; }
  __syncthreads();
  float S  = red[0]+red[1]+red[2]+red[3];
  float SS = red[4]+red[5]+red[6]+red[7];
  float m = S*(1.0f/256.0f);
  float r = rsqrtf(SS*(1.0f/256.0f) - m*m + 1e-5f);
  sn[t] = (v-m)*r*g[t]+bbv[t];
  __syncthreads();
  const uint4* w4 = (const uint4*)(M2h + (size_t)t*256);
  float acc=0.f;
#pragma unroll 4
  for(int kk=0;kk<32;kk++){
    U4 w; w.u=w4[kk];
#pragma unroll
    for(int q=0;q<4;q++){
      float2 f=__half22float2(w.h[q]);
      acc += sn[kk*8+2*q]*f.x + sn[kk*8+2*q+1]*f.y;
    }
  }
  qs[row*256+t]=acc;
}

// ---------------- fused attention: dots+softmax -> w -> partial agg (atomic) ----------------
__global__ __launch_bounds__(256) void k_att(const __half* __restrict__ x, const float* __restrict__ qs,
                                             float* __restrict__ aggF, float* __restrict__ wsumF){
  int b = blockIdx.x>>4;
  int t = threadIdx.x;
  size_t j = (size_t)blockIdx.x*256 + t;
  __shared__ __align__(16) float qt[256][8];
  __shared__ __align__(16) float wl[256][8];
  __shared__ __align__(16) float aggl[4][2048];
  __shared__ float wsl[4][8];
  const float* qb = qs + b*2048;
  for(int e=t;e<2048;e+=256) qt[e&255][e>>8]=qb[e];
  __syncthreads();
  const uint4* xr = (const uint4*)(x + j*DD);
  float pd[8]={0,0,0,0,0,0,0,0};
#pragma unroll 4
  for(int ch=0; ch<32; ch++){
    uint4 u = xr[ch];
    float2 f0=u2f2(u.x), f1=u2f2(u.y), f2=u2f2(u.z), f3=u2f2(u.w);
    float xv[8]={f0.x,f0.y,f1.x,f1.y,f2.x,f2.y,f3.x,f3.y};
    int c0=ch*8;
#pragma unroll
    for(int cc=0;cc<8;cc++){
      const float4* qp=(const float4*)&qt[c0+cc][0];
      float4 qa=qp[0], qc=qp[1];
      float xvv=xv[cc];
      pd[0]+=qa.x*xvv; pd[1]+=qa.y*xvv; pd[2]+=qa.z*xvv; pd[3]+=qa.w*xvv;
      pd[4]+=qc.x*xvv; pd[5]+=qc.y*xvv; pd[6]+=qc.z*xvv; pd[7]+=qc.w*xvv;
    }
  }
  float mx=pd[0];
#pragma unroll
  for(int i=1;i<8;i++) mx=fmaxf(mx,pd[i]);
  float ev[8]; float ssum=0.f;
#pragma unroll
  for(int i=0;i<8;i++){ ev[i]=__expf(pd[i]-mx); ssum+=ev[i]; }
  float inv=1.0f/ssum;
#pragma unroll
  for(int i=0;i<8;i++) wl[t][i]=ev[i]*inv+1e-5f;
  __syncthreads();
  int wid=t>>6, lane=t&63;
  float acc[8][4];
#pragma unroll
  for(int i=0;i<8;i++){ acc[i][0]=0;acc[i][1]=0;acc[i][2]=0;acc[i][3]=0; }
  float ws[8]={0,0,0,0,0,0,0,0};
#pragma unroll 4
  for(int r=0;r<64;r++){
    int jl = wid*64 + r;
    uint2 u = ((const uint2*)(x + ((size_t)blockIdx.x*256 + jl)*DD))[lane];
    float2 f01=u2f2(u.x), f23=u2f2(u.y);
    const float4* wp=(const float4*)&wl[jl][0];
    float4 wa=wp[0], wb_=wp[1];
    float wv[8]={wa.x,wa.y,wa.z,wa.w,wb_.x,wb_.y,wb_.z,wb_.w};
    float xv[4]={f01.x,f01.y,f23.x,f23.y};
#pragma unroll
    for(int i=0;i<8;i++){
      acc[i][0]+=wv[i]*xv[0]; acc[i][1]+=wv[i]*xv[1];
      acc[i][2]+=wv[i]*xv[2]; acc[i][3]+=wv[i]*xv[3];
      ws[i]+=wv[i];
    }
  }
#pragma unroll
  for(int i=0;i<8;i++){
    float4 st={acc[i][0],acc[i][1],acc[i][2],acc[i][3]};
    *((float4*)&aggl[wid][i*256 + lane*4])=st;
  }
  if(lane==0){
#pragma unroll
    for(int i=0;i<8;i++) wsl[wid][i]=ws[i];
  }
  __syncthreads();
  float* ab = aggF + (size_t)b*2048;
  for(int e=t;e<2048;e+=256)
    atomicAdd(&ab[e], aggl[0][e]+aggl[1][e]+aggl[2][e]+aggl[3][e]);
  if(t<8) atomicAdd(&wsumF[b*8+t], wsl[0][t]+wsl[1][t]+wsl[2][t]+wsl[3][t]);
}

// ---------------- t_gates: gl[512][1536] = [(agg*fac)@WC^T+bih | slotsh@Whh^T+bhh] ----------------
__global__ __launch_bounds__(256) void t_gates(const float* __restrict__ aggF,
    const float* __restrict__ wsumF,
    const __half* __restrict__ slotsh, const __half* __restrict__ Wg,
    const float* __restrict__ bih, const float* __restrict__ bhh,
    float* __restrict__ gl){
  int rt=blockIdx.x&15, ct=blockIdx.x>>4;
  int t=threadIdx.x;
  int r0=rt*32, c0=ct*64;
  __shared__ __align__(16) float Af[32][264];
  __shared__ __align__(16) float Wf[64][68];
  __shared__ float facS[32];
  if(ct<12){
    if(t<32) facS[t]=4096.0f/wsumF[r0+t];
    __syncthreads();
#pragma unroll
    for(int q=0;q<8;q++){
      int u=q*256+t;
      int row=u>>6, c4=u&63;
      float4 v=((const float4*)(aggF+(size_t)(r0+row)*256))[c4];
      float f=facS[row];
      v.x*=f; v.y*=f; v.z*=f; v.w*=f;
      *(float4*)&Af[row][c4*4]=v;
    }
  } else {
#pragma unroll
    for(int q=0;q<4;q++){
      int u=q*256+t;
      int row=u>>5, kk=u&31;
      st8(&Af[row][kk*8], ((const uint4*)(slotsh + ((size_t)(r0+row))*256))[kk]);
    }
  }
  float acc[2][4]={{0,0,0,0},{0,0,0,0}};
  int tx=t&15, ty=t>>4;
  for(int kc=0;kc<4;kc++){
    __syncthreads();
#pragma unroll
    for(int q=0;q<2;q++){
      int u=q*256+t;
      int kk=u>>3, cb=u&7;
      st8(&Wf[kk][cb*8], ((const uint4*)(Wg + (size_t)(kc*64+kk)*1536 + c0))[cb]);
    }
    __syncthreads();
#pragma unroll
    for(int k4=0;k4<16;k4++){
      float4 a0=*(const float4*)&Af[ty][kc*64+k4*4];
      float4 a1=*(const float4*)&Af[ty+16][kc*64+k4*4];
      float av0[4]={a0.x,a0.y,a0.z,a0.w};
      float av1[4]={a1.x,a1.y,a1.z,a1.w};
#pragma unroll
      for(int jj=0;jj<4;jj++){
        float4 wv=*(const float4*)&Wf[k4*4+jj][tx*4];
        acc[0][0]+=av0[jj]*wv.x; acc[0][1]+=av0[jj]*wv.y; acc[0][2]+=av0[jj]*wv.z; acc[0][3]+=av0[jj]*wv.w;
        acc[1][0]+=av1[jj]*wv.x; acc[1][1]+=av1[jj]*wv.y; acc[1][2]+=av1[jj]*wv.z; acc[1][3]+=av1[jj]*wv.w;
      }
    }
  }
  int col=c0+tx*4;
  const float* bb=(ct<12)? bih : bhh;
  int bcol=(ct<12)? col : col-768;
  float4 bv=*(const float4*)&bb[bcol];
  float4 o0={acc[0][0]+bv.x, acc[0][1]+bv.y, acc[0][2]+bv.z, acc[0][3]+bv.w};
  float4 o1={acc[1][0]+bv.x, acc[1][1]+bv.y, acc[1][2]+bv.z, acc[1][3]+bv.w};
  *(float4*)&gl[(size_t)(r0+ty)*1536+col]=o0;
  *(float4*)&gl[(size_t)(r0+ty+16)*1536+col]=o1;
}

// ---------------- t_gruln: GRU nonlinearity + MLP pre-norm ----------------
__global__ __launch_bounds__(512) void t_gruln(const float* __restrict__ gl, const float* __restrict__ slots,
    const float* __restrict__ lm_g, const float* __restrict__ lm_b,
    float* __restrict__ hb, __half* __restrict__ ysh){
  int t=threadIdx.x;
  int r=t>>8, c=t&255; int row=blockIdx.x*2+r;
  __shared__ float redS[2][4], redQ[2][4];
  const float* gr = gl + (size_t)row*1536;
  float gir=gr[c], giz=gr[256+c], gin=gr[512+c];
  float ghr=gr[768+c], ghz=gr[1024+c], ghn=gr[1280+c];
  float hp = slots[(size_t)row*256+c];
  float rr=sigm(gir+ghr), z=sigm(giz+ghz);
  float n=tanhf(gin+rr*ghn);
  float hv=(1.0f-z)*n+z*hp;
  hb[(size_t)row*256+c]=hv;
  float s=wredsum(hv), ss=wredsum(hv*hv);
  if((t&63)==0){ redS[r][(t>>6)&3]=s; redQ[r][(t>>6)&3]=ss; }
  __syncthreads();
  float S=redS[r][0]+redS[r][1]+redS[r][2]+redS[r][3];
  float SS=redQ[r][0]+redQ[r][1]+redQ[r][2]+redQ[r][3];
  float m=S*(1.0f/256.0f);
  float rs=rsqrtf(SS*(1.0f/256.0f)-m*m+1e-5f);
  ysh[(size_t)row*256+c]=__float2half((hv-m)*rs*lm_g[c]+lm_b[c]);
}

// ---------------- t_mlp1: z1h[512][1024] = lrelu(ysh@W1^T + b1) ----------------
__global__ __launch_bounds__(256) void t_mlp1(const __half* __restrict__ ysh,
    const __half* __restrict__ W1t, const float* __restrict__ b1,
    __half* __restrict__ z1h){
  int rt=blockIdx.x&15, ct=blockIdx.x>>4;
  int t=threadIdx.x;
  int r0=rt*32, c0=ct*64;
  __shared__ __align__(16) float Af[32][264];
  __shared__ __align__(16) float Wf[64][68];
#pragma unroll
  for(int q=0;q<4;q++){
    int u=q*256+t; int row=u>>5, kk=u&31;
    st8(&Af[row][kk*8], ((const uint4*)(ysh + ((size_t)(r0+row))*256))[kk]);
  }
  float acc[2][4]={{0,0,0,0},{0,0,0,0}};
  int tx=t&15, ty=t>>4;
  for(int kc=0;kc<4;kc++){
    __syncthreads();
#pragma unroll
    for(int q=0;q<2;q++){
      int u=q*256+t; int kk=u>>3, cb=u&7;
      st8(&Wf[kk][cb*8], ((const uint4*)(W1t + (size_t)(kc*64+kk)*1024 + c0))[cb]);
    }
    __syncthreads();
#pragma unroll
    for(int k4=0;k4<16;k4++){
      float4 a0=*(const float4*)&Af[ty][kc*64+k4*4];
      float4 a1=*(const float4*)&Af[ty+16][kc*64+k4*4];
      float av0[4]={a0.x,a0.y,a0.z,a0.w};
      float av1[4]={a1.x,a1.y,a1.z,a1.w};
#pragma unroll
      for(int jj=0;jj<4;jj++){
        float4 wv=*(const float4*)&Wf[k4*4+jj][tx*4];
        acc[0][0]+=av0[jj]*wv.x; acc[0][1]+=av0[jj]*wv.y; acc[0][2]+=av0[jj]*wv.z; acc[0][3]+=av0[jj]*wv.w;
        acc[1][0]+=av1[jj]*wv.x; acc[1][1]+=av1[jj]*wv.y; acc[1][2]+=av1[jj]*wv.z; acc[1][3]+=av1[jj]*wv.w;
      }
    }
  }
  int col=c0+tx*4;
  float4 bv=*(const float4*)&b1[col];
#pragma unroll
  for(int rr2=0;rr2<2;rr2++){
    float v0=acc[rr2][0]+bv.x, v1=acc[rr2][1]+bv.y, v2=acc[rr2][2]+bv.z, v3=acc[rr2][3]+bv.w;
    v0=v0>0.f?v0:0.01f*v0; v1=v1>0.f?v1:0.01f*v1;
    v2=v2>0.f?v2:0.01f*v2; v3=v3>0.f?v3:0.01f*v3;
    __half2 p0=__floats2half2_rn(v0,v1), p1=__floats2half2_rn(v2,v3);
    uint2 u2; __builtin_memcpy(&u2.x,&p0,4); __builtin_memcpy(&u2.y,&p1,4);
    *(uint2*)&z1h[(size_t)(r0+ty+rr2*16)*1024+col]=u2;
  }
}

// ---------------- t_mlp2p: partial z1h@W2^T, K=1024 split 8x128 ----------------
__global__ __launch_bounds__(256) void t_mlp2p(const __half* __restrict__ z1h,
    const __half* __restrict__ W2t, float* __restrict__ pp){
  int b=blockIdx.x;
  int rt=b&15, ct=(b>>4)&3, kc=b>>6;
  int t=threadIdx.x;
  int r0=rt*32, c0=ct*64;
  __shared__ __align__(16) float Af[32][136];
  __shared__ __align__(16) float Wf[128][68];
#pragma unroll
  for(int q=0;q<2;q++){
    int u=q*256+t;
    int row=u>>4, seg=u&15;
    st8(&Af[row][seg*8], ((const uint4*)(z1h + (size_t)(r0+row)*1024 + kc*128))[seg]);
  }
#pragma unroll
  for(int q=0;q<4;q++){
    int u=q*256+t;
    int kk=u>>3, cb=u&7;
    st8(&Wf[kk][cb*8], ((const uint4*)(W2t + (size_t)(kc*128+kk)*256 + c0))[cb]);
  }
  __syncthreads();
  float acc[2][4]={{0,0,0,0},{0,0,0,0}};
  int tx=t&15, ty=t>>4;
#pragma unroll
  for(int k4=0;k4<32;k4++){
    float4 a0=*(const float4*)&Af[ty][k4*4];
    float4 a1=*(const float4*)&Af[ty+16][k4*4];
    float av0[4]={a0.x,a0.y,a0.z,a0.w};
    float av1[4]={a1.x,a1.y,a1.z,a1.w};
#pragma unroll
    for(int jj=0;jj<4;jj++){
      float4 wv=*(const float4*)&Wf[k4*4+jj][tx*4];
      acc[0][0]+=av0[jj]*wv.x; acc[0][1]+=av0[jj]*wv.y; acc[0][2]+=av0[jj]*wv.z; acc[0][3]+=av0[jj]*wv.w;
      acc[1][0]+=av1[jj]*wv.x; acc[1][1]+=av1[jj]*wv.y; acc[1][2]+=av1[jj]*wv.z; acc[1][3]+=av1[jj]*wv.w;
    }
  }
  int col=c0+tx*4;
  float4 o0={acc[0][0],acc[0][1],acc[0][2],acc[0][3]};
  float4 o1={acc[1][0],acc[1][1],acc[1][2],acc[1][3]};
  *(float4*)&pp[((size_t)kc*512 + r0+ty)*256+col]=o0;
  *(float4*)&pp[((size_t)kc*512 + r0+ty+16)*256+col]=o1;
}

// ---------------- t_fin: reduce partials + residual; slot-LN + qs (non-last) ----------------
__global__ __launch_bounds__(512) void t_fin(const float* __restrict__ hb, const float* __restrict__ pp,
    const float* __restrict__ b2, const float* __restrict__ ls_g, const float* __restrict__ ls_b,
    const __half* __restrict__ M2h, float* __restrict__ dst,
    __half* __restrict__ slotsh, float* __restrict__ qs, int last){
  int t=threadIdx.x;
  int r=t>>8, c=t&255; int row=blockIdx.x*2+r;
  __shared__ float ysl[2][256];
  __shared__ float redS[2][4], redQ[2][4];
  float s = hb[(size_t)row*256+c] + b2[c];
#pragma unroll
  for(int kc=0;kc<8;kc++) s += pp[((size_t)kc*512+row)*256+c];
  dst[(size_t)row*256+c]=s;
  if(last) return;
  slotsh[(size_t)row*256+c]=__float2half(s);
  float su=wredsum(s), sq=wredsum(s*s);
  if((t&63)==0){ redS[r][(t>>6)&3]=su; redQ[r][(t>>6)&3]=sq; }
  __syncthreads();
  float S=redS[r][0]+redS[r][1]+redS[r][2]+redS[r][3];
  float SS=redQ[r][0]+redQ[r][1]+redQ[r][2]+redQ[r][3];
  float m=S*(1.0f/256.0f);
  float rs=rsqrtf(SS*(1.0f/256.0f)-m*m+1e-5f);
  ysl[r][c]=(s-m)*rs*ls_g[c]+ls_b[c];
  __syncthreads();
  const uint4* m4=(const uint4*)(M2h+(size_t)c*256);
  float acc=0.f;
#pragma unroll 4
  for(int kk=0;kk<32;kk++){
    U4 w; w.u=m4[kk];
#pragma unroll
    for(int q=0;q<4;q++){
      float2 f=__half22float2(w.h[q]);
      acc += ysl[r][kk*8+2*q]*f.x + ysl[r][kk*8+2*q+1]*f.y;
    }
  }
  qs[(size_t)row*256+c]=acc;
}

extern "C" void kernel_launch(void* const* d_in, const int* in_sizes, int n_in,
                              void* d_out, int out_size, void* d_ws, size_t ws_size,
                              hipStream_t stream){
  const float* inputs=(const float*)d_in[0];
  const float* sinit =(const float*)d_in[1];
  const float* Wq =(const float*)d_in[2];
  const float* Wk =(const float*)d_in[3];
  const float* Wv =(const float*)d_in[4];
  const float* Wih=(const float*)d_in[5];
  const float* Whh=(const float*)d_in[6];
  const float* bih=(const float*)d_in[7];
  const float* bhh=(const float*)d_in[8];
  const float* lin_g=(const float*)d_in[9];
  const float* lin_b=(const float*)d_in[10];
  const float* ls_g=(const float*)d_in[11];
  const float* ls_b=(const float*)d_in[12];
  const float* lm_g=(const float*)d_in[13];
  const float* lm_b=(const float*)d_in[14];
  const float* W1=(const float*)d_in[15];
  const float* b1=(const float*)d_in[16];
  const float* W2=(const float*)d_in[17];
  const float* b2=(const float*)d_in[18];

  char* w=(char*)d_ws;
  __half* x    =(__half*)w; w += (size_t)BB*NN*DD*2;        // 134.2 MB
  float* qs    =(float*)w;  w += 512*256*4;
  float* slots =(float*)w;  w += 512*256*4;
  __half* slotsh=(__half*)w; w += 512*256*2;
  __half* M2h  =(__half*)w; w += 256*256*2;
  __half* Wg   =(__half*)w; w += 256*1536*2;
  __half* W1t  =(__half*)w; w += 256*1024*2;
  __half* W2t  =(__half*)w; w += 1024*256*2;
  float* hb    =(float*)w;  w += 512*256*4;
  __half* ysh  =(__half*)w; w += 512*256*2;
  __half* z1h  =(__half*)w; w += (size_t)512*1024*2;
  float* pp    =(float*)w;  w += (size_t)8*512*256*4;       // 4.2 MB
  float* gl_   =(float*)w;  w += (size_t)512*1536*4;        // 3.1 MB
  float* aggZ  =(float*)w;  w += (size_t)(3*512*256 + 3*512)*4;

  float* aggFv[3]; float* wsumFv[3];
  for(int i=0;i<3;i++){ aggFv[i]=aggZ + (size_t)i*131072; wsumFv[i]=aggZ + 393216 + (size_t)i*512; }

  hipLaunchKernelGGL(kp_all, dim3(4230), dim3(256), 0, stream,
                     Whh, W1, W2, sinit, Wih, Wv, Wq, Wk,
                     Wg, W1t, W2t, slots, M2h, aggZ);
  hipLaunchKernelGGL(k_ln_x, dim3(8192), dim3(256), 0, stream, inputs, lin_g, lin_b, x);
  hipLaunchKernelGGL(k_pre,  dim3(512),  dim3(256), 0, stream, slots, ls_g, ls_b, M2h, qs, slotsh);
  for(int it=0; it<NITER; ++it){
    int last = (it==NITER-1);
    float* dst = last ? (float*)d_out : slots;
    hipLaunchKernelGGL(k_att,   dim3(1024), dim3(256), 0, stream, x, qs, aggFv[it], wsumFv[it]);
    hipLaunchKernelGGL(t_gates, dim3(384),  dim3(256), 0, stream, aggFv[it], wsumFv[it], slotsh, Wg, bih, bhh, gl_);
    hipLaunchKernelGGL(t_gruln, dim3(256),  dim3(512), 0, stream, gl_, slots, lm_g, lm_b, hb, ysh);
    hipLaunchKernelGGL(t_mlp1,  dim3(256),  dim3(256), 0, stream, ysh, W1t, b1, z1h);
    hipLaunchKernelGGL(t_mlp2p, dim3(512),  dim3(256), 0, stream, z1h, W2t, pp);
    hipLaunchKernelGGL(t_fin,   dim3(256),  dim3(512), 0, stream, hb, pp, b2, ls_g, ls_b, M2h,
                       dst, slotsh, qs, last);
  }
}

// Round 17
// 381.332 us; speedup vs baseline: 2.1926x; 1.0254x over previous
//
#include <hip/hip_runtime.h>
#include <hip/hip_fp16.h>
#include <hip/hip_bf16.h>

// SlotAttention restructured:
//  dots = qs . x   with qs = LN(slots) @ (scale * Wq^T Wk)   (K never materialized)
//  updates folded:  gates_ih = (agg*fac) @ (Wih@Wv)^T        (V and upd never materialized)
// x = LN(inputs) fp16. fp32 accumulation. Output fp32.
// Measured structural facts: cross-block sync ~35us (R13), kernel boundary ~6us,
// chunk-machine starves TLP (R12), atomic+last-block fusion loses (R14),
// redundant GRU recompute loses (R15). 5-phase tail is phase-minimal.
// R17 = R16 + kp_all/k_ln_x merged (independent work, prep hides under LN's
// HBM stream). 18 -> 17 dispatches.

#define BB 64
#define NN 4096
#define DD 256
#define NSL 8
#define NITER 3

__device__ __forceinline__ float wredsum(float v){
#pragma unroll
  for(int m=32;m;m>>=1) v += __shfl_xor(v, m, 64);
  return v;
}
__device__ __forceinline__ float2 u2f2(unsigned u){ __half2 h; __builtin_memcpy(&h,&u,4); return __half22float2(h); }
__device__ __forceinline__ float sigm(float v){ return 1.0f/(1.0f+__expf(-v)); }

union U4 { uint4 u; __half2 h[4]; };

__device__ __forceinline__ void st8(float* dst, uint4 uu){
  U4 v; v.u=uu;
  float2 f0=__half22float2(v.h[0]), f1=__half22float2(v.h[1]),
         f2=__half22float2(v.h[2]), f3=__half22float2(v.h[3]);
  dst[0]=f0.x; dst[1]=f0.y; dst[2]=f1.x; dst[3]=f1.y;
  dst[4]=f2.x; dst[5]=f2.y; dst[6]=f3.x; dst[7]=f3.y;
}

// ---------------- merged prep + ln_x: blocks [0,4230)=prep, [4230,12422)=LN ----------------
__global__ __launch_bounds__(256) void kp_ln(
    const float* __restrict__ Whh, const float* __restrict__ W1,
    const float* __restrict__ W2,  const float* __restrict__ sinit,
    const float* __restrict__ Wih, const float* __restrict__ Wv,
    const float* __restrict__ Wq,  const float* __restrict__ Wk,
    __half* __restrict__ Wg, __half* __restrict__ W1t, __half* __restrict__ W2t,
    float* __restrict__ slots, __half* __restrict__ M2h, float* __restrict__ zbuf,
    const float* __restrict__ in, const float* __restrict__ lg,
    const float* __restrict__ lb, __half* __restrict__ x){
  int bid=blockIdx.x, t=threadIdx.x;
  if(bid<1664){
    for(int idx=bid*256+t; idx<851968; idx+=1664*256){
      if(idx<196608){ int col=idx>>8, c=idx&255; Wg[(size_t)c*1536+768+col]=__float2half(Whh[idx]); }
      else if(idx<458752){ int k=idx-196608; int col=k>>8, c=k&255; W1t[(size_t)c*1024+col]=__float2half(W1[k]); }
      else if(idx<720896){ int k=idx-458752; int col=k>>10, c=k&1023; W2t[(size_t)c*256+col]=__float2half(W2[k]); }
      else { int k=idx-720896; slots[k]=sinit[k&2047]; }
    }
  } else if(bid<2432){
    int col=bid-1664;            // 0..767
    __shared__ float wr[256];
    wr[t]=Wih[col*256+t];
    __syncthreads();
    float acc=0.f;
#pragma unroll 8
    for(int d=0;d<256;d++) acc += wr[d]*Wv[d*256+t];
    Wg[(size_t)t*1536+col]=__float2half(acc);
  } else if(bid<2688){
    int c=bid-2432;              // 0..255
    float acc=0.f;
#pragma unroll 8
    for(int d=0;d<256;d++) acc += Wq[d*256+t]*Wk[d*256+c];
    M2h[(size_t)c*256+t]=__float2half(acc*0.0625f);
  } else if(bid<4230){
    int idx=(bid-2688)*256+t;
    if(idx<394752) zbuf[idx]=0.f;
  } else {
    // ---- LN(inputs) -> x fp16, grid-stride over 8192 virtual blocks ----
    int lane = t&63;
    float4 gv = ((const float4*)lg)[lane];
    float4 bv = ((const float4*)lb)[lane];
    for(int row = (bid-4230)*4 + (t>>6); row < BB*NN; row += 8192*4){
      const float4 v = ((const float4*)(in + (size_t)row*DD))[lane];
      float s  = v.x+v.y+v.z+v.w;
      float ss = v.x*v.x+v.y*v.y+v.z*v.z+v.w*v.w;
      s = wredsum(s); ss = wredsum(ss);
      float m = s*(1.0f/256.0f);
      float r = rsqrtf(ss*(1.0f/256.0f) - m*m + 1e-5f);
      float y0=(v.x-m)*r*gv.x+bv.x, y1=(v.y-m)*r*gv.y+bv.y;
      float y2=(v.z-m)*r*gv.z+bv.z, y3=(v.w-m)*r*gv.w+bv.w;
      __half2 h0=__floats2half2_rn(y0,y1), h1=__floats2half2_rn(y2,y3);
      uint2 u; __builtin_memcpy(&u.x,&h0,4); __builtin_memcpy(&u.y,&h1,4);
      ((uint2*)(x + (size_t)row*DD))[lane] = u;
    }
  }
}

// ---------------- initial qs = LN(slots) @ M (once); also writes slotsh ----------------
__global__ __launch_bounds__(256) void k_pre(const float* __restrict__ slots, const float* __restrict__ g,
                                             const float* __restrict__ bbv, const __half* __restrict__ M2h,
                                             float* __restrict__ qs, __half* __restrict__ slotsh){
  int row = blockIdx.x;      // 0..511
  int t = threadIdx.x;
  __shared__ __align__(16) float sn[256];
  __shared__ float red[8];
  float v = slots[row*256 + t];
  slotsh[(size_t)row*256+t]=__float2half(v);
  float s = wredsum(v), ss = wredsum(v*v);
  int wid=t>>6, lane=t&63;
  if(lane==0){ red[wid]=s; red[4+wid]=ss; }
  __syncthreads();
  float S  = red[0]+red[1]+red[2]+red[3];
  float SS = red[4]+red[5]+red[6]+red[7];
  float m = S*(1.0f/256.0f);
  float r = rsqrtf(SS*(1.0f/256.0f) - m*m + 1e-5f);
  sn[t] = (v-m)*r*g[t]+bbv[t];
  __syncthreads();
  const uint4* w4 = (const uint4*)(M2h + (size_t)t*256);
  float acc=0.f;
#pragma unroll 4
  for(int kk=0;kk<32;kk++){
    U4 w; w.u=w4[kk];
#pragma unroll
    for(int q=0;q<4;q++){
      float2 f=__half22float2(w.h[q]);
      acc += sn[kk*8+2*q]*f.x + sn[kk*8+2*q+1]*f.y;
    }
  }
  qs[row*256+t]=acc;
}

// ---------------- fused attention: dots+softmax -> w -> partial agg (atomic) ----------------
__global__ __launch_bounds__(256) void k_att(const __half* __restrict__ x, const float* __restrict__ qs,
                                             float* __restrict__ aggF, float* __restrict__ wsumF){
  int b = blockIdx.x>>4;
  int t = threadIdx.x;
  size_t j = (size_t)blockIdx.x*256 + t;
  __shared__ __align__(16) float qt[256][8];
  __shared__ __align__(16) float wl[256][8];
  __shared__ __align__(16) float aggl[4][2048];
  __shared__ float wsl[4][8];
  const float* qb = qs + b*2048;
  for(int e=t;e<2048;e+=256) qt[e&255][e>>8]=qb[e];
  __syncthreads();
  const uint4* xr = (const uint4*)(x + j*DD);
  float pd[8]={0,0,0,0,0,0,0,0};
#pragma unroll 4
  for(int ch=0; ch<32; ch++){
    uint4 u = xr[ch];
    float2 f0=u2f2(u.x), f1=u2f2(u.y), f2=u2f2(u.z), f3=u2f2(u.w);
    float xv[8]={f0.x,f0.y,f1.x,f1.y,f2.x,f2.y,f3.x,f3.y};
    int c0=ch*8;
#pragma unroll
    for(int cc=0;cc<8;cc++){
      const float4* qp=(const float4*)&qt[c0+cc][0];
      float4 qa=qp[0], qc=qp[1];
      float xvv=xv[cc];
      pd[0]+=qa.x*xvv; pd[1]+=qa.y*xvv; pd[2]+=qa.z*xvv; pd[3]+=qa.w*xvv;
      pd[4]+=qc.x*xvv; pd[5]+=qc.y*xvv; pd[6]+=qc.z*xvv; pd[7]+=qc.w*xvv;
    }
  }
  float mx=pd[0];
#pragma unroll
  for(int i=1;i<8;i++) mx=fmaxf(mx,pd[i]);
  float ev[8]; float ssum=0.f;
#pragma unroll
  for(int i=0;i<8;i++){ ev[i]=__expf(pd[i]-mx); ssum+=ev[i]; }
  float inv=1.0f/ssum;
#pragma unroll
  for(int i=0;i<8;i++) wl[t][i]=ev[i]*inv+1e-5f;
  __syncthreads();
  int wid=t>>6, lane=t&63;
  float acc[8][4];
#pragma unroll
  for(int i=0;i<8;i++){ acc[i][0]=0;acc[i][1]=0;acc[i][2]=0;acc[i][3]=0; }
  float ws[8]={0,0,0,0,0,0,0,0};
#pragma unroll 4
  for(int r=0;r<64;r++){
    int jl = wid*64 + r;
    uint2 u = ((const uint2*)(x + ((size_t)blockIdx.x*256 + jl)*DD))[lane];
    float2 f01=u2f2(u.x), f23=u2f2(u.y);
    const float4* wp=(const float4*)&wl[jl][0];
    float4 wa=wp[0], wb_=wp[1];
    float wv[8]={wa.x,wa.y,wa.z,wa.w,wb_.x,wb_.y,wb_.z,wb_.w};
    float xv[4]={f01.x,f01.y,f23.x,f23.y};
#pragma unroll
    for(int i=0;i<8;i++){
      acc[i][0]+=wv[i]*xv[0]; acc[i][1]+=wv[i]*xv[1];
      acc[i][2]+=wv[i]*xv[2]; acc[i][3]+=wv[i]*xv[3];
      ws[i]+=wv[i];
    }
  }
#pragma unroll
  for(int i=0;i<8;i++){
    float4 st={acc[i][0],acc[i][1],acc[i][2],acc[i][3]};
    *((float4*)&aggl[wid][i*256 + lane*4])=st;
  }
  if(lane==0){
#pragma unroll
    for(int i=0;i<8;i++) wsl[wid][i]=ws[i];
  }
  __syncthreads();
  float* ab = aggF + (size_t)b*2048;
  for(int e=t;e<2048;e+=256)
    atomicAdd(&ab[e], aggl[0][e]+aggl[1][e]+aggl[2][e]+aggl[3][e]);
  if(t<8) atomicAdd(&wsumF[b*8+t], wsl[0][t]+wsl[1][t]+wsl[2][t]+wsl[3][t]);
}

// ---------------- t_gates: gl[512][1536] = [(agg*fac)@WC^T+bih | slotsh@Whh^T+bhh] ----------------
__global__ __launch_bounds__(256) void t_gates(const float* __restrict__ aggF,
    const float* __restrict__ wsumF,
    const __half* __restrict__ slotsh, const __half* __restrict__ Wg,
    const float* __restrict__ bih, const float* __restrict__ bhh,
    float* __restrict__ gl){
  int rt=blockIdx.x&15, ct=blockIdx.x>>4;
  int t=threadIdx.x;
  int r0=rt*32, c0=ct*64;
  __shared__ __align__(16) float Af[32][264];
  __shared__ __align__(16) float Wf[64][68];
  __shared__ float facS[32];
  if(ct<12){
    if(t<32) facS[t]=4096.0f/wsumF[r0+t];
    __syncthreads();
#pragma unroll
    for(int q=0;q<8;q++){
      int u=q*256+t;
      int row=u>>6, c4=u&63;
      float4 v=((const float4*)(aggF+(size_t)(r0+row)*256))[c4];
      float f=facS[row];
      v.x*=f; v.y*=f; v.z*=f; v.w*=f;
      *(float4*)&Af[row][c4*4]=v;
    }
  } else {
#pragma unroll
    for(int q=0;q<4;q++){
      int u=q*256+t;
      int row=u>>5, kk=u&31;
      st8(&Af[row][kk*8], ((const uint4*)(slotsh + ((size_t)(r0+row))*256))[kk]);
    }
  }
  float acc[2][4]={{0,0,0,0},{0,0,0,0}};
  int tx=t&15, ty=t>>4;
  for(int kc=0;kc<4;kc++){
    __syncthreads();
#pragma unroll
    for(int q=0;q<2;q++){
      int u=q*256+t;
      int kk=u>>3, cb=u&7;
      st8(&Wf[kk][cb*8], ((const uint4*)(Wg + (size_t)(kc*64+kk)*1536 + c0))[cb]);
    }
    __syncthreads();
#pragma unroll
    for(int k4=0;k4<16;k4++){
      float4 a0=*(const float4*)&Af[ty][kc*64+k4*4];
      float4 a1=*(const float4*)&Af[ty+16][kc*64+k4*4];
      float av0[4]={a0.x,a0.y,a0.z,a0.w};
      float av1[4]={a1.x,a1.y,a1.z,a1.w};
#pragma unroll
      for(int jj=0;jj<4;jj++){
        float4 wv=*(const float4*)&Wf[k4*4+jj][tx*4];
        acc[0][0]+=av0[jj]*wv.x; acc[0][1]+=av0[jj]*wv.y; acc[0][2]+=av0[jj]*wv.z; acc[0][3]+=av0[jj]*wv.w;
        acc[1][0]+=av1[jj]*wv.x; acc[1][1]+=av1[jj]*wv.y; acc[1][2]+=av1[jj]*wv.z; acc[1][3]+=av1[jj]*wv.w;
      }
    }
  }
  int col=c0+tx*4;
  const float* bb=(ct<12)? bih : bhh;
  int bcol=(ct<12)? col : col-768;
  float4 bv=*(const float4*)&bb[bcol];
  float4 o0={acc[0][0]+bv.x, acc[0][1]+bv.y, acc[0][2]+bv.z, acc[0][3]+bv.w};
  float4 o1={acc[1][0]+bv.x, acc[1][1]+bv.y, acc[1][2]+bv.z, acc[1][3]+bv.w};
  *(float4*)&gl[(size_t)(r0+ty)*1536+col]=o0;
  *(float4*)&gl[(size_t)(r0+ty+16)*1536+col]=o1;
}

// ---------------- t_gruln: GRU nonlinearity + MLP pre-norm ----------------
__global__ __launch_bounds__(512) void t_gruln(const float* __restrict__ gl, const float* __restrict__ slots,
    const float* __restrict__ lm_g, const float* __restrict__ lm_b,
    float* __restrict__ hb, __half* __restrict__ ysh){
  int t=threadIdx.x;
  int r=t>>8, c=t&255; int row=blockIdx.x*2+r;
  __shared__ float redS[2][4], redQ[2][4];
  const float* gr = gl + (size_t)row*1536;
  float gir=gr[c], giz=gr[256+c], gin=gr[512+c];
  float ghr=gr[768+c], ghz=gr[1024+c], ghn=gr[1280+c];
  float hp = slots[(size_t)row*256+c];
  float rr=sigm(gir+ghr), z=sigm(giz+ghz);
  float n=tanhf(gin+rr*ghn);
  float hv=(1.0f-z)*n+z*hp;
  hb[(size_t)row*256+c]=hv;
  float s=wredsum(hv), ss=wredsum(hv*hv);
  if((t&63)==0){ redS[r][(t>>6)&3]=s; redQ[r][(t>>6)&3]=ss; }
  __syncthreads();
  float S=redS[r][0]+redS[r][1]+redS[r][2]+redS[r][3];
  float SS=redQ[r][0]+redQ[r][1]+redQ[r][2]+redQ[r][3];
  float m=S*(1.0f/256.0f);
  float rs=rsqrtf(SS*(1.0f/256.0f)-m*m+1e-5f);
  ysh[(size_t)row*256+c]=__float2half((hv-m)*rs*lm_g[c]+lm_b[c]);
}

// ---------------- t_mlp1: z1h[512][1024] = lrelu(ysh@W1^T + b1) ----------------
__global__ __launch_bounds__(256) void t_mlp1(const __half* __restrict__ ysh,
    const __half* __restrict__ W1t, const float* __restrict__ b1,
    __half* __restrict__ z1h){
  int rt=blockIdx.x&15, ct=blockIdx.x>>4;
  int t=threadIdx.x;
  int r0=rt*32, c0=ct*64;
  __shared__ __align__(16) float Af[32][264];
  __shared__ __align__(16) float Wf[64][68];
#pragma unroll
  for(int q=0;q<4;q++){
    int u=q*256+t; int row=u>>5, kk=u&31;
    st8(&Af[row][kk*8], ((const uint4*)(ysh + ((size_t)(r0+row))*256))[kk]);
  }
  float acc[2][4]={{0,0,0,0},{0,0,0,0}};
  int tx=t&15, ty=t>>4;
  for(int kc=0;kc<4;kc++){
    __syncthreads();
#pragma unroll
    for(int q=0;q<2;q++){
      int u=q*256+t; int kk=u>>3, cb=u&7;
      st8(&Wf[kk][cb*8], ((const uint4*)(W1t + (size_t)(kc*64+kk)*1024 + c0))[cb]);
    }
    __syncthreads();
#pragma unroll
    for(int k4=0;k4<16;k4++){
      float4 a0=*(const float4*)&Af[ty][kc*64+k4*4];
      float4 a1=*(const float4*)&Af[ty+16][kc*64+k4*4];
      float av0[4]={a0.x,a0.y,a0.z,a0.w};
      float av1[4]={a1.x,a1.y,a1.z,a1.w};
#pragma unroll
      for(int jj=0;jj<4;jj++){
        float4 wv=*(const float4*)&Wf[k4*4+jj][tx*4];
        acc[0][0]+=av0[jj]*wv.x; acc[0][1]+=av0[jj]*wv.y; acc[0][2]+=av0[jj]*wv.z; acc[0][3]+=av0[jj]*wv.w;
        acc[1][0]+=av1[jj]*wv.x; acc[1][1]+=av1[jj]*wv.y; acc[1][2]+=av1[jj]*wv.z; acc[1][3]+=av1[jj]*wv.w;
      }
    }
  }
  int col=c0+tx*4;
  float4 bv=*(const float4*)&b1[col];
#pragma unroll
  for(int rr2=0;rr2<2;rr2++){
    float v0=acc[rr2][0]+bv.x, v1=acc[rr2][1]+bv.y, v2=acc[rr2][2]+bv.z, v3=acc[rr2][3]+bv.w;
    v0=v0>0.f?v0:0.01f*v0; v1=v1>0.f?v1:0.01f*v1;
    v2=v2>0.f?v2:0.01f*v2; v3=v3>0.f?v3:0.01f*v3;
    __half2 p0=__floats2half2_rn(v0,v1), p1=__floats2half2_rn(v2,v3);
    uint2 u2; __builtin_memcpy(&u2.x,&p0,4); __builtin_memcpy(&u2.y,&p1,4);
    *(uint2*)&z1h[(size_t)(r0+ty+rr2*16)*1024+col]=u2;
  }
}

// ---------------- t_mlp2p: partial z1h@W2^T, K=1024 split 8x128 ----------------
__global__ __launch_bounds__(256) void t_mlp2p(const __half* __restrict__ z1h,
    const __half* __restrict__ W2t, float* __restrict__ pp){
  int b=blockIdx.x;
  int rt=b&15, ct=(b>>4)&3, kc=b>>6;
  int t=threadIdx.x;
  int r0=rt*32, c0=ct*64;
  __shared__ __align__(16) float Af[32][136];
  __shared__ __align__(16) float Wf[128][68];
#pragma unroll
  for(int q=0;q<2;q++){
    int u=q*256+t;
    int row=u>>4, seg=u&15;
    st8(&Af[row][seg*8], ((const uint4*)(z1h + (size_t)(r0+row)*1024 + kc*128))[seg]);
  }
#pragma unroll
  for(int q=0;q<4;q++){
    int u=q*256+t;
    int kk=u>>3, cb=u&7;
    st8(&Wf[kk][cb*8], ((const uint4*)(W2t + (size_t)(kc*128+kk)*256 + c0))[cb]);
  }
  __syncthreads();
  float acc[2][4]={{0,0,0,0},{0,0,0,0}};
  int tx=t&15, ty=t>>4;
#pragma unroll
  for(int k4=0;k4<32;k4++){
    float4 a0=*(const float4*)&Af[ty][k4*4];
    float4 a1=*(const float4*)&Af[ty+16][k4*4];
    float av0[4]={a0.x,a0.y,a0.z,a0.w};
    float av1[4]={a1.x,a1.y,a1.z,a1.w};
#pragma unroll
    for(int jj=0;jj<4;jj++){
      float4 wv=*(const float4*)&Wf[k4*4+jj][tx*4];
      acc[0][0]+=av0[jj]*wv.x; acc[0][1]+=av0[jj]*wv.y; acc[0][2]+=av0[jj]*wv.z; acc[0][3]+=av0[jj]*wv.w;
      acc[1][0]+=av1[jj]*wv.x; acc[1][1]+=av1[jj]*wv.y; acc[1][2]+=av1[jj]*wv.z; acc[1][3]+=av1[jj]*wv.w;
    }
  }
  int col=c0+tx*4;
  float4 o0={acc[0][0],acc[0][1],acc[0][2],acc[0][3]};
  float4 o1={acc[1][0],acc[1][1],acc[1][2],acc[1][3]};
  *(float4*)&pp[((size_t)kc*512 + r0+ty)*256+col]=o0;
  *(float4*)&pp[((size_t)kc*512 + r0+ty+16)*256+col]=o1;
}

// ---------------- t_fin: reduce partials + residual; slot-LN + qs (non-last) ----------------
__global__ __launch_bounds__(512) void t_fin(const float* __restrict__ hb, const float* __restrict__ pp,
    const float* __restrict__ b2, const float* __restrict__ ls_g, const float* __restrict__ ls_b,
    const __half* __restrict__ M2h, float* __restrict__ dst,
    __half* __restrict__ slotsh, float* __restrict__ qs, int last){
  int t=threadIdx.x;
  int r=t>>8, c=t&255; int row=blockIdx.x*2+r;
  __shared__ float ysl[2][256];
  __shared__ float redS[2][4], redQ[2][4];
  float s = hb[(size_t)row*256+c] + b2[c];
#pragma unroll
  for(int kc=0;kc<8;kc++) s += pp[((size_t)kc*512+row)*256+c];
  dst[(size_t)row*256+c]=s;
  if(last) return;
  slotsh[(size_t)row*256+c]=__float2half(s);
  float su=wredsum(s), sq=wredsum(s*s);
  if((t&63)==0){ redS[r][(t>>6)&3]=su; redQ[r][(t>>6)&3]=sq; }
  __syncthreads();
  float S=redS[r][0]+redS[r][1]+redS[r][2]+redS[r][3];
  float SS=redQ[r][0]+redQ[r][1]+redQ[r][2]+redQ[r][3];
  float m=S*(1.0f/256.0f);
  float rs=rsqrtf(SS*(1.0f/256.0f)-m*m+1e-5f);
  ysl[r][c]=(s-m)*rs*ls_g[c]+ls_b[c];
  __syncthreads();
  const uint4* m4=(const uint4*)(M2h+(size_t)c*256);
  float acc=0.f;
#pragma unroll 4
  for(int kk=0;kk<32;kk++){
    U4 w; w.u=m4[kk];
#pragma unroll
    for(int q=0;q<4;q++){
      float2 f=__half22float2(w.h[q]);
      acc += ysl[r][kk*8+2*q]*f.x + ysl[r][kk*8+2*q+1]*f.y;
    }
  }
  qs[(size_t)row*256+c]=acc;
}

extern "C" void kernel_launch(void* const* d_in, const int* in_sizes, int n_in,
                              void* d_out, int out_size, void* d_ws, size_t ws_size,
                              hipStream_t stream){
  const float* inputs=(const float*)d_in[0];
  const float* sinit =(const float*)d_in[1];
  const float* Wq =(const float*)d_in[2];
  const float* Wk =(const float*)d_in[3];
  const float* Wv =(const float*)d_in[4];
  const float* Wih=(const float*)d_in[5];
  const float* Whh=(const float*)d_in[6];
  const float* bih=(const float*)d_in[7];
  const float* bhh=(const float*)d_in[8];
  const float* lin_g=(const float*)d_in[9];
  const float* lin_b=(const float*)d_in[10];
  const float* ls_g=(const float*)d_in[11];
  const float* ls_b=(const float*)d_in[12];
  const float* lm_g=(const float*)d_in[13];
  const float* lm_b=(const float*)d_in[14];
  const float* W1=(const float*)d_in[15];
  const float* b1=(const float*)d_in[16];
  const float* W2=(const float*)d_in[17];
  const float* b2=(const float*)d_in[18];

  char* w=(char*)d_ws;
  __half* x    =(__half*)w; w += (size_t)BB*NN*DD*2;        // 134.2 MB
  float* qs    =(float*)w;  w += 512*256*4;
  float* slots =(float*)w;  w += 512*256*4;
  __half* slotsh=(__half*)w; w += 512*256*2;
  __half* M2h  =(__half*)w; w += 256*256*2;
  __half* Wg   =(__half*)w; w += 256*1536*2;
  __half* W1t  =(__half*)w; w += 256*1024*2;
  __half* W2t  =(__half*)w; w += 1024*256*2;
  float* hb    =(float*)w;  w += 512*256*4;
  __half* ysh  =(__half*)w; w += 512*256*2;
  __half* z1h  =(__half*)w; w += (size_t)512*1024*2;
  float* pp    =(float*)w;  w += (size_t)8*512*256*4;       // 4.2 MB
  float* gl_   =(float*)w;  w += (size_t)512*1536*4;        // 3.1 MB
  float* aggZ  =(float*)w;  w += (size_t)(3*512*256 + 3*512)*4;

  float* aggFv[3]; float* wsumFv[3];
  for(int i=0;i<3;i++){ aggFv[i]=aggZ + (size_t)i*131072; wsumFv[i]=aggZ + 393216 + (size_t)i*512; }

  hipLaunchKernelGGL(kp_ln, dim3(12422), dim3(256), 0, stream,
                     Whh, W1, W2, sinit, Wih, Wv, Wq, Wk,
                     Wg, W1t, W2t, slots, M2h, aggZ,
                     inputs, lin_g, lin_b, x);
  hipLaunchKernelGGL(k_pre,  dim3(512),  dim3(256), 0, stream, slots, ls_g, ls_b, M2h, qs, slotsh);
  for(int it=0; it<NITER; ++it){
    int last = (it==NITER-1);
    float* dst = last ? (float*)d_out : slots;
    hipLaunchKernelGGL(k_att,   dim3(1024), dim3(256), 0, stream, x, qs, aggFv[it], wsumFv[it]);
    hipLaunchKernelGGL(t_gates, dim3(384),  dim3(256), 0, stream, aggFv[it], wsumFv[it], slotsh, Wg, bih, bhh, gl_);
    hipLaunchKernelGGL(t_gruln, dim3(256),  dim3(512), 0, stream, gl_, slots, lm_g, lm_b, hb, ysh);
    hipLaunchKernelGGL(t_mlp1,  dim3(256),  dim3(256), 0, stream, ysh, W1t, b1, z1h);
    hipLaunchKernelGGL(t_mlp2p, dim3(512),  dim3(256), 0, stream, z1h, W2t, pp);
    hipLaunchKernelGGL(t_fin,   dim3(256),  dim3(512), 0, stream, hb, pp, b2, ls_g, ls_b, M2h,
                       dst, slotsh, qs, last);
  }
}